// Round 13
// baseline (127.534 us; speedup 1.0000x reference)
//
#include <hip/hip_runtime.h>
#include <math.h>

#define NOBJ 52
#define LL 24
#define NHEAD 12

typedef __attribute__((ext_vector_type(8))) short bf16x8;
typedef __attribute__((ext_vector_type(4))) float f32x4;
typedef __attribute__((ext_vector_type(4))) unsigned int u32x4;
typedef __attribute__((ext_vector_type(2))) unsigned int u32x2;

__device__ __forceinline__ unsigned short f2b(float x) {
    union { float f; unsigned int u; } v; v.f = x;
    unsigned int r = v.u + 0x7fffu + ((v.u >> 16) & 1u);
    return (unsigned short)(r >> 16);
}
__device__ __forceinline__ float b2f(unsigned short u) {
    union { unsigned int u; float f; } v; v.u = ((unsigned int)u) << 16;
    return v.f;
}
__device__ __forceinline__ unsigned int pack2(float a, float b) {
    return (unsigned int)f2b(a) | ((unsigned int)f2b(b) << 16);
}
__device__ __forceinline__ f32x4 mfma16(bf16x8 a, bf16x8 b, f32x4 c) {
    return __builtin_amdgcn_mfma_f32_16x16x32_bf16(a, b, c, 0, 0, 0);
}
__device__ __forceinline__ void gl_lds16(const void* g, void* lds) {
    __builtin_amdgcn_global_load_lds(
        (const __attribute__((address_space(1))) unsigned int*)g,
        (__attribute__((address_space(3))) unsigned int*)lds, 16, 0, 0);
}

// ---------------------------------------------------------------------------
// 64x64 transpose tile: f32 [K][N] -> bf16 [N][K]
// ---------------------------------------------------------------------------
__device__ __forceinline__ void transpose_tile(const float* __restrict__ src,
    unsigned short* __restrict__ dst, int K, int N, int t, char* smem)
{
    float (*ts)[65] = (float(*)[65])smem;
    const int tid = threadIdx.x;
    const int ntk = K >> 6;
    const int k0 = (t % ntk) << 6, n0 = (t / ntk) << 6;
    const int tx = tid & 63, ty = tid >> 6;
    #pragma unroll
    for (int i2 = 0; i2 < 16; ++i2) {
        const int row = i2 * 4 + ty;
        ts[row][tx] = src[(size_t)(k0 + row) * N + n0 + tx];
    }
    __syncthreads();
    #pragma unroll
    for (int i2 = 0; i2 < 16; ++i2) {
        const int row = i2 * 4 + ty;
        dst[(size_t)(n0 + row) * K + k0 + tx] = f2b(ts[tx][row]);
    }
}

// ---------------------------------------------------------------------------
// pack1: 8 square weight transposes [0,1152) + activation/bias pack [1152,...)
// ---------------------------------------------------------------------------
__global__ __launch_bounds__(256)
void pack1_kernel(const float* s0, const float* s1, const float* s2,
                  const float* s3, const float* s4, const float* s5,
                  const float* s6, const float* s7,
                  unsigned short* d0, unsigned short* d1, unsigned short* d2,
                  unsigned short* d3, unsigned short* d4, unsigned short* d5,
                  unsigned short* d6, unsigned short* d7,
                  const float* obj, const float* lang, const float* n_bq,
                  const float* e_bk, const float* e_bv,
                  const float* n_bk, const float* n_bv,
                  unsigned short* objb, unsigned short* langb,
                  float* bqc, float* blc)
{
    __shared__ __align__(16) char smem[16640];
    const int bid = blockIdx.x;
    const int tid = threadIdx.x;
    if (bid < 1152) {
        const int job = bid / 144, t = bid % 144;
        const float* src; unsigned short* dst;
        switch (job) {
            case 0: src = s0; dst = d0; break;
            case 1: src = s1; dst = d1; break;
            case 2: src = s2; dst = d2; break;
            case 3: src = s3; dst = d3; break;
            case 4: src = s4; dst = d4; break;
            case 5: src = s5; dst = d5; break;
            case 6: src = s6; dst = d6; break;
            default: src = s7; dst = d7; break;
        }
        transpose_tile(src, dst, 768, 768, t, smem);
    } else {
        const int base = ((bid - 1152) * 256 + tid) * 4;
        const int T0 = 638976, T1 = 933888, T2 = 935424, T3 = 938496;
        if (base >= T3) return;
        if (base < T0) {
            f32x4 v = *(const f32x4*)(obj + base);
            *(u32x2*)(objb + base) = (u32x2){pack2(v[0], v[1]), pack2(v[2], v[3])};
        } else if (base < T1) {
            const int j = base - T0;
            f32x4 v = *(const f32x4*)(lang + j);
            *(u32x2*)(langb + j) = (u32x2){pack2(v[0], v[1]), pack2(v[2], v[3])};
        } else if (base < T2) {
            const int j = base - T1;
            if (j < 768) { *(f32x4*)(bqc + j) = (f32x4){0.f, 0.f, 0.f, 0.f}; }
            else         { *(f32x4*)(bqc + j) = *(const f32x4*)(n_bq + j - 768); }
        } else {
            const int j = base - T2;
            const int s = j / 768, c = j % 768;
            const float* p = (s == 0) ? e_bk : (s == 1) ? e_bv : (s == 2) ? n_bk : n_bv;
            *(f32x4*)(blc + j) = *(const f32x4*)(p + c);
        }
    }
}

// ---------------------------------------------------------------------------
// Generic GEMM: C[M,N] = A[M,K](bf16) @ Bt[N,K-slice]^T + bias (+relu).
// 64x128 tile, BK=64, dbuf global_load_lds, chunk-XOR swizzle. 256 thr.
// ---------------------------------------------------------------------------
struct GemmJob {
    const unsigned short* A; const unsigned short* Bt; const float* bias;
    float* C; unsigned short* Cb;
    int lda, ldb, ldc, K, nbx, nb, relu, swz;
};

__device__ __forceinline__ void gemm_body(const GemmJob J, int bid, char* smem)
{
    unsigned short* As = (unsigned short*)smem;             // 2 x 4096
    unsigned short* Bs = (unsigned short*)(smem + 16384);   // 2 x 8192
    int bx, by;
    if (J.swz) {
        const int cpx = J.nb >> 3;
        const int gid = (bid & 7) * cpx + (bid >> 3);
        const int nbm = J.nb / J.nbx;
        bx = gid / nbm; by = gid % nbm;
    } else { bx = bid % J.nbx; by = bid / J.nbx; }
    const int n0 = bx * 128, m0 = by * 64;
    const int tid = threadIdx.x;
    const int lane = tid & 63;
    const int w = tid >> 6, wr = w >> 1, wc = w & 1;
    const int lr = lane & 15, lk = lane >> 4;
    const int lda = J.lda, ldb = J.ldb, K = J.K;
    const unsigned short* Ab = J.A + (size_t)m0 * lda;
    const unsigned short* Bb = J.Bt + (size_t)n0 * ldb;

    f32x4 acc[2][4] = {};
    const int NT = K >> 6;

    #pragma unroll
    for (int q = 0; q < 2; ++q) {
        const int c = q * 256 + tid, row = c >> 3, p = (c & 7) ^ (row & 7);
        gl_lds16(Ab + (size_t)row * lda + p * 8, As + c * 8);
    }
    #pragma unroll
    for (int q = 0; q < 4; ++q) {
        const int c = q * 256 + tid, row = c >> 3, p = (c & 7) ^ (row & 7);
        gl_lds16(Bb + (size_t)row * ldb + p * 8, Bs + c * 8);
    }
    __syncthreads();

    for (int t = 0; t < NT; ++t) {
        const int cur = t & 1;
        if (t + 1 < NT) {
            const int k0 = (t + 1) << 6;
            #pragma unroll
            for (int q = 0; q < 2; ++q) {
                const int c = q * 256 + tid, row = c >> 3, p = (c & 7) ^ (row & 7);
                gl_lds16(Ab + (size_t)row * lda + k0 + p * 8, As + (cur ^ 1) * 4096 + c * 8);
            }
            #pragma unroll
            for (int q = 0; q < 4; ++q) {
                const int c = q * 256 + tid, row = c >> 3, p = (c & 7) ^ (row & 7);
                gl_lds16(Bb + (size_t)row * ldb + k0 + p * 8, Bs + (cur ^ 1) * 8192 + c * 8);
            }
        }
        #pragma unroll
        for (int kk = 0; kk < 2; ++kk) {
            bf16x8 af[2], bv[4];
            #pragma unroll
            for (int mt = 0; mt < 2; ++mt) {
                const int row = wr * 32 + mt * 16 + lr;
                const int pc = (kk * 4 + lk) ^ (row & 7);
                af[mt] = *(const bf16x8*)(As + cur * 4096 + row * 64 + pc * 8);
            }
            #pragma unroll
            for (int nt = 0; nt < 4; ++nt) {
                const int col = wc * 64 + nt * 16 + lr;
                const int pc = (kk * 4 + lk) ^ (col & 7);
                bv[nt] = *(const bf16x8*)(Bs + cur * 8192 + col * 64 + pc * 8);
            }
            #pragma unroll
            for (int mt = 0; mt < 2; ++mt)
                #pragma unroll
                for (int nt = 0; nt < 4; ++nt)
                    acc[mt][nt] = mfma16(af[mt], bv[nt], acc[mt][nt]);
        }
        __syncthreads();
    }

    #pragma unroll
    for (int mt = 0; mt < 2; ++mt) {
        #pragma unroll
        for (int nt = 0; nt < 4; ++nt) {
            const int col = n0 + wc * 64 + nt * 16 + lr;
            const float bvv = J.bias ? J.bias[col] : 0.f;
            #pragma unroll
            for (int r = 0; r < 4; ++r) {
                const int row = m0 + wr * 32 + mt * 16 + lk * 4 + r;
                float v = acc[mt][nt][r] + bvv;
                if (J.relu) v = fmaxf(v, 0.f);
                if (J.C)  J.C[(size_t)row * J.ldc + col] = v;
                if (J.Cb) J.Cb[(size_t)row * J.ldc + col] = f2b(v);
            }
        }
    }
}

__global__ __launch_bounds__(256)
void gemm_tn4(GemmJob j0, GemmJob j1, GemmJob j2, GemmJob j3)
{
    __shared__ __align__(16) char smem[49152];
    int bid = blockIdx.x;
    if (bid < j0.nb) { gemm_body(j0, bid, smem); return; }
    bid -= j0.nb;
    if (bid < j1.nb) { gemm_body(j1, bid, smem); return; }
    bid -= j1.nb;
    if (bid < j2.nb) { gemm_body(j2, bid, smem); return; }
    bid -= j2.nb;
    gemm_body(j3, bid, smem);
}

// ---------------------------------------------------------------------------
// proj_pack: [0,nb0+nb1) projection GEMMs; then ffn weight transposes
// ---------------------------------------------------------------------------
__global__ __launch_bounds__(256)
void proj_pack_kernel(GemmJob j0, GemmJob j1,
                      const float* w1, const float* w2,
                      unsigned short* W1t, unsigned short* W2t)
{
    __shared__ __align__(16) char smem[49152];
    int bid = blockIdx.x;
    if (bid < j0.nb) { gemm_body(j0, bid, smem); return; }
    bid -= j0.nb;
    if (bid < j1.nb) { gemm_body(j1, bid, smem); return; }
    const int t = bid - j1.nb;
    if (t < 768) transpose_tile(w1, W1t, 1536, 2048, t, smem);
    else transpose_tile(w2, W2t, 2048, 768, t - 768, smem);
}

// ---------------------------------------------------------------------------
// mid3: [0,216) VWe GEMM; [216,432) VWn GEMM; [432,624) S2e+T; [624,816) S2n
// S2 written TRANSPOSED: S2[n][h][l][q] (q fastest) for coalesced softmax
// ---------------------------------------------------------------------------
__global__ __launch_bounds__(256)
void mid3_kernel(const unsigned short* __restrict__ QCb,
                 const unsigned short* __restrict__ LCb,
                 const unsigned short* __restrict__ Wet,
                 const unsigned short* __restrict__ Wot,
                 const float* __restrict__ e_bq,
                 unsigned short* __restrict__ VWe,
                 unsigned short* __restrict__ VWn,
                 float* __restrict__ S2e, float* __restrict__ Tb,
                 float* __restrict__ S2n)
{
    __shared__ __align__(16) union USm {
        struct { unsigned short As[8192], Bs[8192]; } g;
        unsigned short Ct[128 * 136];
        struct { float sA[52][65], sB[24][65]; } s;
    } U;
    const int bid = blockIdx.x;
    const int tid = threadIdx.x;

    if (bid < 432) {
        const int sub = bid >= 216;
        const int b = sub ? bid - 216 : bid;
        const int aoff = sub ? 2304 : 768;
        const unsigned short* Bt = sub ? Wot : Wet;
        unsigned short* Vout = sub ? VWn : VWe;

        const int h = b / 18, rm = b % 18, mt = rm / 6, ntile = rm % 6;
        const int m0 = mt * 128, n0 = ntile * 128;
        const int lane = tid & 63, w = tid >> 6, wr = w >> 1, wc = w & 1;
        const int lr = lane & 15, lk = lane >> 4;
        #pragma unroll
        for (int q = 0; q < 4; ++q) {
            const int c = q * 256 + tid, row = c >> 3, p = (c & 7) ^ (row & 7);
            gl_lds16(LCb + (size_t)(m0 + row) * 3072 + aoff + h * 64 + p * 8, &U.g.As[c * 8]);
            gl_lds16(Bt + (size_t)(n0 + row) * 768 + h * 64 + p * 8, &U.g.Bs[c * 8]);
        }
        __syncthreads();
        f32x4 acc[4][4] = {};
        #pragma unroll
        for (int kk = 0; kk < 2; ++kk) {
            bf16x8 af[4], bv[4];
            #pragma unroll
            for (int m2 = 0; m2 < 4; ++m2) {
                const int row = wr * 64 + m2 * 16 + lr;
                const int pc = (kk * 4 + lk) ^ (row & 7);
                af[m2] = *(const bf16x8*)&U.g.As[row * 64 + pc * 8];
            }
            #pragma unroll
            for (int n2 = 0; n2 < 4; ++n2) {
                const int col = wc * 64 + n2 * 16 + lr;
                const int pc = (kk * 4 + lk) ^ (col & 7);
                bv[n2] = *(const bf16x8*)&U.g.Bs[col * 64 + pc * 8];
            }
            #pragma unroll
            for (int m2 = 0; m2 < 4; ++m2)
                #pragma unroll
                for (int n2 = 0; n2 < 4; ++n2)
                    acc[m2][n2] = mfma16(af[m2], bv[n2], acc[m2][n2]);
        }
        __syncthreads();
        #pragma unroll
        for (int m2 = 0; m2 < 4; ++m2)
            #pragma unroll
            for (int n2 = 0; n2 < 4; ++n2) {
                const int col = wc * 64 + n2 * 16 + lr;
                #pragma unroll
                for (int r = 0; r < 4; ++r) {
                    const int row = wr * 64 + m2 * 16 + lk * 4 + r;
                    U.Ct[row * 136 + col] = f2b(acc[m2][n2][r]);
                }
            }
        __syncthreads();
        #pragma unroll
        for (int q = 0; q < 8; ++q) {
            const int item = q * 256 + tid;
            const int dl = item & 127, kg = item >> 7;
            const int m = m0 + kg * 8;
            const int nn = m / 24, l0 = m % 24;
            const int kc = (h * 24 + l0) >> 3;
            const int ks = kc >> 2;
            const int dg = n0 + dl;
            const int kpos = (kc & 3) ^ ((dg >> 1) & 3);
            u32x4 uu;
            #pragma unroll
            for (int e = 0; e < 4; ++e)
                uu[e] = (unsigned int)U.Ct[(kg * 8 + 2 * e) * 136 + dl]
                      | ((unsigned int)U.Ct[(kg * 8 + 2 * e + 1) * 136 + dl] << 16);
            *(u32x4*)(Vout + (size_t)nn * 221184 + ks * 24576 + dg * 32 + kpos * 8) = uu;
        }
    } else {
        const int sub = bid >= 624;               // 0: S2e(+T), 1: S2n
        const int b = bid - (sub ? 624 : 432);
        const int n = b / NHEAD, h = b % NHEAD;
        const int qoff = sub ? 768 : 0, koff = sub ? 1536 : 0;
        float* Sout = sub ? S2n : S2e;
        for (int p = tid; p < 52 * 64; p += 256) {
            const int q = p >> 6, d = p & 63;
            U.s.sA[q][d] = b2f(QCb[(size_t)(n * 52 + q) * 1536 + qoff + h * 64 + d]);
        }
        for (int p = tid; p < 24 * 64; p += 256) {
            const int l = p >> 6, d = p & 63;
            U.s.sB[l][d] = b2f(LCb[(size_t)(n * 24 + l) * 3072 + koff + h * 64 + d]);
        }
        __syncthreads();
        for (int p = tid; p < 52 * 24; p += 256) {
            const int l = p / 52, q = p % 52;       // transposed: l slow, q fast
            float s = 0.f;
            #pragma unroll
            for (int d = 0; d < 64; ++d) s += U.s.sA[q][d] * U.s.sB[l][d];
            Sout[((size_t)(n * NHEAD + h) * 24 + l) * 52 + q] = s;
        }
        if (!sub && tid < 24) {
            float s = 0.f;
            #pragma unroll
            for (int d = 0; d < 64; ++d) s += e_bq[h * 64 + d] * U.s.sB[tid][d];
            Tb[((size_t)n * NHEAD + h) * 24 + tid] = s;
        }
    }
}

// ---------------------------------------------------------------------------
// attn_kernel v5: full-width blocks + FUSED residual layernorm.
// [0,416): edge, block = (n, i-pair), 512 thr / 8 waves (2 i x 4 col-groups
//   of 192). Softmax once per (n,i); B = full 768-col VW panel dbuf.
//   Epilogue: max-over-j + e_bo -> LDS maxbuf (over dead Pf) ->
//   LN(obj + edge) -> Fusedb[:,768:1536] directly (ln_e).
// [416,432): node, block = (n). Epilogue: acc+n_bo -> LDS bf16 [52][768]
//   (over dead Bs; preserves bf16 round-trip numerics) -> wave-per-row
//   LN(obj + node) -> Fusedb[:,0:768] (ln_q).
// ---------------------------------------------------------------------------
__global__ __launch_bounds__(512)
void attn_kernel(const float* __restrict__ S2e, const float* __restrict__ Tb,
                 const float* __restrict__ S2n, const int* __restrict__ co_mask,
                 const unsigned short* __restrict__ VWe,
                 const unsigned short* __restrict__ VWn,
                 const float* __restrict__ ebo, const float* __restrict__ nbo,
                 const float* __restrict__ obj,
                 const float* __restrict__ gq, const float* __restrict__ bq,
                 const float* __restrict__ ge, const float* __restrict__ be,
                 unsigned short* __restrict__ Fusedb)
{
    __shared__ __align__(16) char smem[161760];
    unsigned short* Pf = (unsigned short*)smem;              // [2][52*288] = 59904 B
    unsigned short* Bs = (unsigned short*)(smem + 59904);    // 2 x 24576 shorts = 98304 B
    float* SiT = (float*)(smem + 158208);                    // [2][288] = 2304 B
    unsigned char* cmb = (unsigned char*)(smem + 160512);    // 1248 B
    // epilogue overlays (dead regions):
    float* maxbuf = (float*)smem;                            // [2][768] f32 over Pf
    float* redbuf = (float*)(smem + 6144);                   // [8] over Pf tail
    unsigned short* nodeLDS = (unsigned short*)(smem + 59904); // [52][768] bf16 over Bs
    const int bid = blockIdx.x;
    const int tid = threadIdx.x;
    const int lane = tid & 63, w = tid >> 6;
    const int lr = lane & 15, lk = lane >> 4;

    if (bid < 416) {
        const int sw = (bid & 7) * 52 + (bid >> 3);          // XCD-contiguous n
        const int n = sw / 26;
        const int ip = sw % 26;
        const int i0 = ip * 2;
        const unsigned short* Bsrc = VWe + (size_t)n * 221184;
        const float* S2x = S2e + (size_t)n * NHEAD * 24 * 52;   // [h][l][j]

        // stage B ks=0 early (hides under softmax)
        #pragma unroll
        for (int q = 0; q < 6; ++q) {
            const int c = q * 512 + tid;
            gl_lds16(Bsrc + c * 8, Bs + c * 8);
        }
        for (int p = tid; p < 576; p += 512) {
            const int ii = p >= 288 ? 1 : 0;
            const int rl = p - ii * 288;                     // h*24 + l
            SiT[ii * 288 + rl] = S2x[(size_t)rl * 52 + i0 + ii]
                               + Tb[(size_t)n * 288 + rl];
        }
        for (int p = tid; p < 1248; p += 512)
            cmb[p] = (unsigned char)(co_mask[(size_t)n * 1248 + p] > 0);
        __syncthreads();

        // softmax rows (ii,h,j) -> Pf[ii], swizzled chunk layout — ONCE
        for (int p = tid; p < 1248; p += 512) {
            const int ii = p >= 624 ? 1 : 0;
            const int rl = p - ii * 624;
            const int h = rl / 52, j = rl % 52;
            const float* Sc = S2x + (size_t)h * 1248 + j;    // stride 52 over l
            const float* st = SiT + ii * 288 + h * 24;
            float x[24]; float mx = -1e30f;
            #pragma unroll
            for (int l = 0; l < 24; ++l) {
                float v = (st[l] - Sc[l * 52]) * 0.125f;
                v = cmb[l * 52 + j] ? v : -1e9f;
                x[l] = v; mx = fmaxf(mx, v);
            }
            float sum = 0.f;
            #pragma unroll
            for (int l = 0; l < 24; ++l) { const float e = __expf(x[l] - mx); x[l] = e; sum += e; }
            const float inv = 1.f / sum;
            unsigned short* Prow = Pf + ii * 14976 + j * 288;
            const int swk = (j >> 1) & 3;
            #pragma unroll
            for (int c = 0; c < 3; ++c) {
                u32x4 u;
                #pragma unroll
                for (int m = 0; m < 4; ++m)
                    u[m] = pack2(x[c * 8 + 2 * m] * inv, x[c * 8 + 2 * m + 1] * inv);
                *(u32x4*)(Prow + (((3 * h + c) ^ swk) << 3)) = u;
            }
        }
        __syncthreads();

        const int iw = w >> 2, cg = (w & 3) * 192;
        f32x4 acc[4][12] = {};
        for (int ks = 0; ks < 9; ++ks) {
            const int cur = ks & 1;
            if (ks < 8) {
                const unsigned short* src = Bsrc + (size_t)(ks + 1) * 24576;
                #pragma unroll
                for (int q = 0; q < 6; ++q) {
                    const int c = q * 512 + tid;
                    gl_lds16(src + c * 8, Bs + (cur ^ 1) * 24576 + c * 8);
                }
            }
            bf16x8 af[4];
            #pragma unroll
            for (int mt = 0; mt < 4; ++mt) {
                const int row = mt * 16 + lr;
                const int rowc = row < NOBJ ? row : 0;       // clamp pad rows
                af[mt] = *(const bf16x8*)(Pf + iw * 14976 + rowc * 288
                                          + (((ks * 4 + lk) ^ ((rowc >> 1) & 3)) << 3));
            }
            #pragma unroll
            for (int nt = 0; nt < 12; ++nt) {
                const int cl = cg + nt * 16 + lr;
                bf16x8 bv = *(const bf16x8*)(Bs + cur * 24576 + cl * 32
                                             + ((lk ^ ((cl >> 1) & 3)) << 3));
                #pragma unroll
                for (int mt = 0; mt < 4; ++mt)
                    acc[mt][nt] = mfma16(af[mt], bv, acc[mt][nt]);
            }
            __syncthreads();
        }

        // epilogue: max-over-j + e_bo -> maxbuf (Pf region is dead)
        #pragma unroll
        for (int nt = 0; nt < 12; ++nt) {
            float m = -1e30f;
            #pragma unroll
            for (int mt = 0; mt < 4; ++mt)
                #pragma unroll
                for (int r = 0; r < 4; ++r) {
                    const int row = mt * 16 + lk * 4 + r;
                    if (row < NOBJ) m = fmaxf(m, acc[mt][nt][r]);
                }
            m = fmaxf(m, __shfl_xor(m, 16));
            m = fmaxf(m, __shfl_xor(m, 32));
            if (lk == 0) {
                const int col = cg + nt * 16 + lr;
                maxbuf[iw * 768 + col] = b2f(f2b(m + ebo[col]));
            }
        }
        __syncthreads();

        // fused LN(obj + edge) -> Fusedb[:,768:1536] for rows i0, i0+1
        for (int r = 0; r < 2; ++r) {
            const float* objr = obj + (size_t)(n * 52 + i0 + r) * 768;
            const float v0 = maxbuf[r * 768 + tid] + objr[tid];
            const float v1 = (tid < 256) ? maxbuf[r * 768 + 512 + tid] + objr[512 + tid] : 0.f;
            float s = v0 + v1;
            #pragma unroll
            for (int o = 32; o; o >>= 1) s += __shfl_xor(s, o);
            if (lane == 0) redbuf[w] = s;
            __syncthreads();
            float mean = 0.f;
            #pragma unroll
            for (int k = 0; k < 8; ++k) mean += redbuf[k];
            mean *= (1.f / 768.f);
            const float d0 = v0 - mean;
            const float d1 = (tid < 256) ? v1 - mean : 0.f;
            float var = d0 * d0 + d1 * d1;
            #pragma unroll
            for (int o = 32; o; o >>= 1) var += __shfl_xor(var, o);
            __syncthreads();
            if (lane == 0) redbuf[w] = var;
            __syncthreads();
            float vt = 0.f;
            #pragma unroll
            for (int k = 0; k < 8; ++k) vt += redbuf[k];
            const float rs = rsqrtf(vt * (1.f / 768.f) + 1e-5f);
            unsigned short* dst = Fusedb + (size_t)(n * 52 + i0 + r) * 1536 + 768;
            dst[tid] = f2b(d0 * rs * ge[tid] + be[tid]);
            if (tid < 256) dst[512 + tid] = f2b(d1 * rs * ge[512 + tid] + be[512 + tid]);
            __syncthreads();
        }
    } else {
        const int n = bid - 416;
        const unsigned short* Bsrc = VWn + (size_t)n * 221184;
        const float* S2x = S2n + (size_t)n * NHEAD * 24 * 52;   // [h][l][j]

        #pragma unroll
        for (int q = 0; q < 6; ++q) {
            const int c = q * 512 + tid;
            gl_lds16(Bsrc + c * 8, Bs + c * 8);
        }
        for (int p = tid; p < 1248; p += 512)
            cmb[p] = (unsigned char)(co_mask[(size_t)n * 1248 + p] > 0);
        __syncthreads();

        for (int p = tid; p < 624; p += 512) {
            const int h = p / 52, q = p % 52;
            const float* Sc = S2x + (size_t)h * 1248 + q;
            float x[24]; float mx = -1e30f;
            #pragma unroll
            for (int l = 0; l < 24; ++l) {
                float v = Sc[l * 52] * 0.125f;
                v = cmb[l * 52 + q] ? v : -1e9f;
                x[l] = v; mx = fmaxf(mx, v);
            }
            float sum = 0.f;
            #pragma unroll
            for (int l = 0; l < 24; ++l) { const float e = __expf(x[l] - mx); x[l] = e; sum += e; }
            const float inv = 1.f / sum;
            unsigned short* Prow = Pf + q * 288;
            const int swk = (q >> 1) & 3;
            #pragma unroll
            for (int c = 0; c < 3; ++c) {
                u32x4 u;
                #pragma unroll
                for (int m = 0; m < 4; ++m)
                    u[m] = pack2(x[c * 8 + 2 * m] * inv, x[c * 8 + 2 * m + 1] * inv);
                *(u32x4*)(Prow + (((3 * h + c) ^ swk) << 3)) = u;
            }
        }
        __syncthreads();

        const int cg = w * 96;
        f32x4 acc[4][6] = {};
        for (int ks = 0; ks < 9; ++ks) {
            const int cur = ks & 1;
            if (ks < 8) {
                const unsigned short* src = Bsrc + (size_t)(ks + 1) * 24576;
                #pragma unroll
                for (int q = 0; q < 6; ++q) {
                    const int c = q * 512 + tid;
                    gl_lds16(src + c * 8, Bs + (cur ^ 1) * 24576 + c * 8);
                }
            }
            bf16x8 af[4];
            #pragma unroll
            for (int mt = 0; mt < 4; ++mt) {
                const int row = mt * 16 + lr;
                const int rowc = row < NOBJ ? row : 0;
                af[mt] = *(const bf16x8*)(Pf + rowc * 288
                                          + (((ks * 4 + lk) ^ ((rowc >> 1) & 3)) << 3));
            }
            #pragma unroll
            for (int nt = 0; nt < 6; ++nt) {
                const int cl = cg + nt * 16 + lr;
                bf16x8 bv = *(const bf16x8*)(Bs + cur * 24576 + cl * 32
                                             + ((lk ^ ((cl >> 1) & 3)) << 3));
                #pragma unroll
                for (int mt = 0; mt < 4; ++mt)
                    acc[mt][nt] = mfma16(af[mt], bv, acc[mt][nt]);
            }
            __syncthreads();
        }

        // epilogue: acc + n_bo -> nodeLDS bf16 (Bs region is dead)
        #pragma unroll
        for (int nt = 0; nt < 6; ++nt) {
            const int col = cg + nt * 16 + lr;
            const float bv = nbo[col];
            #pragma unroll
            for (int mt = 0; mt < 4; ++mt)
                #pragma unroll
                for (int r = 0; r < 4; ++r) {
                    const int row = mt * 16 + lk * 4 + r;
                    if (row < NOBJ)
                        nodeLDS[row * 768 + col] = f2b(acc[mt][nt][r] + bv);
                }
        }
        __syncthreads();

        // fused LN(obj + node) -> Fusedb[:,0:768], wave per row
        for (int rr = w; rr < NOBJ; rr += 8) {
            const float* objr = obj + (size_t)(n * 52 + rr) * 768;
            float v[12]; float s = 0.f;
            #pragma unroll
            for (int c = 0; c < 12; ++c) {
                const int col = lane + 64 * c;
                v[c] = objr[col] + b2f(nodeLDS[rr * 768 + col]);
                s += v[c];
            }
            #pragma unroll
            for (int o = 32; o; o >>= 1) s += __shfl_xor(s, o);
            const float mean = s * (1.f / 768.f);
            float var = 0.f;
            #pragma unroll
            for (int c = 0; c < 12; ++c) { const float d = v[c] - mean; var += d * d; }
            #pragma unroll
            for (int o = 32; o; o >>= 1) var += __shfl_xor(var, o);
            const float rs = rsqrtf(var * (1.f / 768.f) + 1e-5f);
            unsigned short* dst = Fusedb + (size_t)(n * 52 + rr) * 1536;
            #pragma unroll
            for (int c = 0; c < 12; ++c) {
                const int col = lane + 64 * c;
                dst[col] = f2b((v[c] - mean) * rs * gq[col] + bq[col]);
            }
        }
    }
}

// ---------------------------------------------------------------------------
// final LN: out = LN(Fusedb + sum of 4 ffn2 K-partials + ffn_b2)
// ---------------------------------------------------------------------------
__global__ __launch_bounds__(256)
void ln2_kernel(const unsigned short* __restrict__ x1b,
                const float* __restrict__ Hp, const float* __restrict__ b2,
                const float* __restrict__ g, const float* __restrict__ bb,
                float* __restrict__ dst)
{
    __shared__ float red[8];
    const int row = blockIdx.x, tid = threadIdx.x;
    float v[3]; float s = 0.f;
    #pragma unroll
    for (int c = 0; c < 3; ++c) {
        const int col = tid + 256 * c;
        const size_t o = (size_t)row * 768 + col;
        float h = Hp[o] + Hp[638976 + o] + Hp[2 * 638976 + o] + Hp[3 * 638976 + o];
        v[c] = b2f(x1b[(size_t)row * 1536 + col]) + h + b2[col];
        s += v[c];
    }
    #pragma unroll
    for (int o = 32; o; o >>= 1) s += __shfl_xor(s, o);
    if ((tid & 63) == 0) red[tid >> 6] = s;
    __syncthreads();
    const float mean = (red[0] + red[1] + red[2] + red[3]) * (1.f / 768.f);
    float var = 0.f;
    #pragma unroll
    for (int c = 0; c < 3; ++c) { const float d = v[c] - mean; var += d * d; }
    #pragma unroll
    for (int o = 32; o; o >>= 1) var += __shfl_xor(var, o);
    __syncthreads();
    if ((tid & 63) == 0) red[4 + (tid >> 6)] = var;
    __syncthreads();
    const float vt = (red[4] + red[5] + red[6] + red[7]) * (1.f / 768.f);
    const float rs = rsqrtf(vt + 1e-5f);
    #pragma unroll
    for (int c = 0; c < 3; ++c) {
        const int col = tid + 256 * c;
        dst[(size_t)row * 768 + col] = (v[c] - mean) * rs * g[col] + bb[col];
    }
}

// ---------------------------------------------------------------------------
extern "C" void kernel_launch(void* const* d_in, const int* in_sizes, int n_in,
                              void* d_out, int out_size, void* d_ws, size_t ws_size,
                              hipStream_t stream)
{
    (void)in_sizes; (void)n_in; (void)out_size; (void)ws_size;
    const float* lang  = (const float*)d_in[0];
    const float* obj   = (const float*)d_in[1];
    const int* co_mask = (const int*)d_in[4];
    const float* e_wq = (const float*)d_in[5];
    const float* e_bq = (const float*)d_in[6];
    const float* e_wk = (const float*)d_in[7];
    const float* e_bk = (const float*)d_in[8];
    const float* e_wv = (const float*)d_in[9];
    const float* e_bv = (const float*)d_in[10];
    const float* e_wo = (const float*)d_in[11];
    const float* e_bo = (const float*)d_in[12];
    const float* n_wq = (const float*)d_in[13];
    const float* n_bq = (const float*)d_in[14];
    const float* n_wk = (const float*)d_in[15];
    const float* n_bk = (const float*)d_in[16];
    const float* n_wv = (const float*)d_in[17];
    const float* n_bv = (const float*)d_in[18];
    const float* n_wo = (const float*)d_in[19];
    const float* n_bo = (const float*)d_in[20];
    const float* ffn_w1 = (const float*)d_in[21];
    const float* ffn_b1 = (const float*)d_in[22];
    const float* ffn_w2 = (const float*)d_in[23];
    const float* ffn_b2 = (const float*)d_in[24];
    const float* ln_e_g = (const float*)d_in[25];
    const float* ln_e_b = (const float*)d_in[26];
    const float* ln_q_g = (const float*)d_in[27];
    const float* ln_q_b = (const float*)d_in[28];
    const float* ln2_g = (const float*)d_in[29];
    const float* ln2_b = (const float*)d_in[30];
    float* out = (float*)d_out;

    // ---- workspace layout (flat, ~58 MB of ~256 MB) ----
    char* wsb = (char*)d_ws;
    unsigned short* Wqt   = (unsigned short*)(wsb + 0);          // [1536][768]
    unsigned short* Wlt   = (unsigned short*)(wsb + 2359296);    // [3072][768]
    unsigned short* Wet   = (unsigned short*)(wsb + 7077888);    // [768][768]
    unsigned short* Wot   = (unsigned short*)(wsb + 8257536);    // [768][768]
    unsigned short* W1t   = (unsigned short*)(wsb + 9437184);    // [2048][1536]
    unsigned short* W2t   = (unsigned short*)(wsb + 15728640);   // [768][2048]
    unsigned short* objb  = (unsigned short*)(wsb + 18874368);   // [832][768]
    unsigned short* langb = (unsigned short*)(wsb + 20152320);   // [384][768]
    float*          bqc   = (float*)(wsb + 20742144);            // [1536]
    float*          blc   = (float*)(wsb + 20748288);            // [3072]
    unsigned short* QCb   = (unsigned short*)(wsb + 20760576);   // [832][1536]
    unsigned short* LCb   = (unsigned short*)(wsb + 23316480);   // [384][3072]
    float*          S2e   = (float*)(wsb + 25675776);            // [16][12][24][52]
    float*          Tb    = (float*)(wsb + 26634240);            // [16][12][24]
    float*          S2n   = (float*)(wsb + 26652672);            // [16][12][24][52]
    unsigned short* VWe   = (unsigned short*)(wsb + 27611136);   // 16*221184
    unsigned short* VWn   = (unsigned short*)(wsb + 34689024);   // 16*221184
    unsigned short* Fusedb= (unsigned short*)(wsb + 41766912);   // [832][1536]
    unsigned short* H1b   = (unsigned short*)(wsb + 44322816);   // [832][2048]
    float*          Hp    = (float*)(wsb + 47730688);            // 4x[832][768] f32

    dim3 blk(256);
    // L1: pack square weights + activations + fused biases
    pack1_kernel<<<2069, blk, 0, stream>>>(
        e_wq, n_wq, e_wk, e_wv, n_wk, n_wv, n_wo, e_wo,
        Wqt, Wqt + 589824, Wlt, Wlt + 589824, Wlt + 2 * 589824, Wlt + 3 * 589824,
        Wot, Wet,
        obj, lang, n_bq, e_bk, e_bv, n_bk, n_bv, objb, langb, bqc, blc);
    // L2: both input projections + FFN weight transposes (independent filler)
    {
        GemmJob p0 = {objb, Wqt, bqc, nullptr, QCb, 768, 768, 1536, 768, 12, 156, 0, 0};
        GemmJob p1 = {langb, Wlt, blc, nullptr, LCb, 768, 768, 3072, 768, 24, 144, 0, 0};
        proj_pack_kernel<<<1452, blk, 0, stream>>>(p0, p1, ffn_w1, ffn_w2, W1t, W2t);
    }
    // L3: VWe + VWn (MFMA) + S2e/T + S2n (transposed S2 layout)
    mid3_kernel<<<816, blk, 0, stream>>>(QCb, LCb, Wet, Wot, e_bq,
                                         VWe, VWn, S2e, Tb, S2n);
    // L4: fused softmax + A@VW + residual layernorms -> Fusedb
    attn_kernel<<<432, dim3(512), 0, stream>>>(S2e, Tb, S2n, co_mask, VWe, VWn,
                                               e_bo, n_bo, obj,
                                               ln_q_g, ln_q_b, ln_e_g, ln_e_b,
                                               Fusedb);
    // L5: FFN1
    {
        GemmJob p0 = {Fusedb, W1t, ffn_b1, nullptr, H1b, 1536, 1536, 2048, 1536, 16, 208, 1, 1};
        gemm_tn4<<<208, blk, 0, stream>>>(p0, p0, p0, p0);
    }
    // L6: FFN2 K-split x4 -> f32 partials
    {
        GemmJob q0 = {H1b,        W2t,        nullptr, Hp,               nullptr, 2048, 2048, 768, 512, 6, 78, 0, 0};
        GemmJob q1 = {H1b + 512,  W2t + 512,  nullptr, Hp + 638976,      nullptr, 2048, 2048, 768, 512, 6, 78, 0, 0};
        GemmJob q2 = {H1b + 1024, W2t + 1024, nullptr, Hp + 2 * 638976,  nullptr, 2048, 2048, 768, 512, 6, 78, 0, 0};
        GemmJob q3 = {H1b + 1536, W2t + 1536, nullptr, Hp + 3 * 638976,  nullptr, 2048, 2048, 768, 512, 6, 78, 0, 0};
        gemm_tn4<<<312, blk, 0, stream>>>(q0, q1, q2, q3);
    }
    // L7: final LN (sums partials + bias)
    ln2_kernel<<<832, blk, 0, stream>>>(Fusedb, Hp, ffn_b2, ln2_g, ln2_b, out);
}

// Round 14
// 123.353 us; speedup vs baseline: 1.0339x; 1.0339x over previous
//
#include <hip/hip_runtime.h>
#include <math.h>

#define NOBJ 52
#define LL 24
#define NHEAD 12

typedef __attribute__((ext_vector_type(8))) short bf16x8;
typedef __attribute__((ext_vector_type(4))) float f32x4;
typedef __attribute__((ext_vector_type(4))) unsigned int u32x4;
typedef __attribute__((ext_vector_type(2))) unsigned int u32x2;

__device__ __forceinline__ unsigned short f2b(float x) {
    union { float f; unsigned int u; } v; v.f = x;
    unsigned int r = v.u + 0x7fffu + ((v.u >> 16) & 1u);
    return (unsigned short)(r >> 16);
}
__device__ __forceinline__ float b2f(unsigned short u) {
    union { unsigned int u; float f; } v; v.u = ((unsigned int)u) << 16;
    return v.f;
}
__device__ __forceinline__ unsigned int pack2(float a, float b) {
    return (unsigned int)f2b(a) | ((unsigned int)f2b(b) << 16);
}
__device__ __forceinline__ f32x4 mfma16(bf16x8 a, bf16x8 b, f32x4 c) {
    return __builtin_amdgcn_mfma_f32_16x16x32_bf16(a, b, c, 0, 0, 0);
}
__device__ __forceinline__ void gl_lds16(const void* g, void* lds) {
    __builtin_amdgcn_global_load_lds(
        (const __attribute__((address_space(1))) unsigned int*)g,
        (__attribute__((address_space(3))) unsigned int*)lds, 16, 0, 0);
}

// ---------------------------------------------------------------------------
// 64x64 transpose tile: f32 [K][N] -> bf16 [N][K]
// ---------------------------------------------------------------------------
__device__ __forceinline__ void transpose_tile(const float* __restrict__ src,
    unsigned short* __restrict__ dst, int K, int N, int t, char* smem)
{
    float (*ts)[65] = (float(*)[65])smem;
    const int tid = threadIdx.x;
    const int ntk = K >> 6;
    const int k0 = (t % ntk) << 6, n0 = (t / ntk) << 6;
    const int tx = tid & 63, ty = tid >> 6;
    #pragma unroll
    for (int i2 = 0; i2 < 16; ++i2) {
        const int row = i2 * 4 + ty;
        ts[row][tx] = src[(size_t)(k0 + row) * N + n0 + tx];
    }
    __syncthreads();
    #pragma unroll
    for (int i2 = 0; i2 < 16; ++i2) {
        const int row = i2 * 4 + ty;
        dst[(size_t)(n0 + row) * K + k0 + tx] = f2b(ts[tx][row]);
    }
}

// ---------------------------------------------------------------------------
// pack1: 8 square weight transposes [0,1152) + activation/bias pack [1152,...)
// ---------------------------------------------------------------------------
__global__ __launch_bounds__(256)
void pack1_kernel(const float* s0, const float* s1, const float* s2,
                  const float* s3, const float* s4, const float* s5,
                  const float* s6, const float* s7,
                  unsigned short* d0, unsigned short* d1, unsigned short* d2,
                  unsigned short* d3, unsigned short* d4, unsigned short* d5,
                  unsigned short* d6, unsigned short* d7,
                  const float* obj, const float* lang, const float* n_bq,
                  const float* e_bk, const float* e_bv,
                  const float* n_bk, const float* n_bv,
                  unsigned short* objb, unsigned short* langb,
                  float* bqc, float* blc)
{
    __shared__ __align__(16) char smem[16640];
    const int bid = blockIdx.x;
    const int tid = threadIdx.x;
    if (bid < 1152) {
        const int job = bid / 144, t = bid % 144;
        const float* src; unsigned short* dst;
        switch (job) {
            case 0: src = s0; dst = d0; break;
            case 1: src = s1; dst = d1; break;
            case 2: src = s2; dst = d2; break;
            case 3: src = s3; dst = d3; break;
            case 4: src = s4; dst = d4; break;
            case 5: src = s5; dst = d5; break;
            case 6: src = s6; dst = d6; break;
            default: src = s7; dst = d7; break;
        }
        transpose_tile(src, dst, 768, 768, t, smem);
    } else {
        const int base = ((bid - 1152) * 256 + tid) * 4;
        const int T0 = 638976, T1 = 933888, T2 = 935424, T3 = 938496;
        if (base >= T3) return;
        if (base < T0) {
            f32x4 v = *(const f32x4*)(obj + base);
            *(u32x2*)(objb + base) = (u32x2){pack2(v[0], v[1]), pack2(v[2], v[3])};
        } else if (base < T1) {
            const int j = base - T0;
            f32x4 v = *(const f32x4*)(lang + j);
            *(u32x2*)(langb + j) = (u32x2){pack2(v[0], v[1]), pack2(v[2], v[3])};
        } else if (base < T2) {
            const int j = base - T1;
            if (j < 768) { *(f32x4*)(bqc + j) = (f32x4){0.f, 0.f, 0.f, 0.f}; }
            else         { *(f32x4*)(bqc + j) = *(const f32x4*)(n_bq + j - 768); }
        } else {
            const int j = base - T2;
            const int s = j / 768, c = j % 768;
            const float* p = (s == 0) ? e_bk : (s == 1) ? e_bv : (s == 2) ? n_bk : n_bv;
            *(f32x4*)(blc + j) = *(const f32x4*)(p + c);
        }
    }
}

// ---------------------------------------------------------------------------
// Generic GEMM: C[M,N] = A[M,K](bf16) @ Bt[N,K-slice]^T + bias (+relu).
// 64x128 tile, BK=64, dbuf global_load_lds, chunk-XOR swizzle. 256 thr.
// ---------------------------------------------------------------------------
struct GemmJob {
    const unsigned short* A; const unsigned short* Bt; const float* bias;
    float* C; unsigned short* Cb;
    int lda, ldb, ldc, K, nbx, nb, relu, swz;
};

__device__ __forceinline__ void gemm_body(const GemmJob J, int bid, char* smem)
{
    unsigned short* As = (unsigned short*)smem;             // 2 x 4096
    unsigned short* Bs = (unsigned short*)(smem + 16384);   // 2 x 8192
    int bx, by;
    if (J.swz) {
        const int cpx = J.nb >> 3;
        const int gid = (bid & 7) * cpx + (bid >> 3);
        const int nbm = J.nb / J.nbx;
        bx = gid / nbm; by = gid % nbm;
    } else { bx = bid % J.nbx; by = bid / J.nbx; }
    const int n0 = bx * 128, m0 = by * 64;
    const int tid = threadIdx.x;
    const int lane = tid & 63;
    const int w = tid >> 6, wr = w >> 1, wc = w & 1;
    const int lr = lane & 15, lk = lane >> 4;
    const int lda = J.lda, ldb = J.ldb, K = J.K;
    const unsigned short* Ab = J.A + (size_t)m0 * lda;
    const unsigned short* Bb = J.Bt + (size_t)n0 * ldb;

    f32x4 acc[2][4] = {};
    const int NT = K >> 6;

    #pragma unroll
    for (int q = 0; q < 2; ++q) {
        const int c = q * 256 + tid, row = c >> 3, p = (c & 7) ^ (row & 7);
        gl_lds16(Ab + (size_t)row * lda + p * 8, As + c * 8);
    }
    #pragma unroll
    for (int q = 0; q < 4; ++q) {
        const int c = q * 256 + tid, row = c >> 3, p = (c & 7) ^ (row & 7);
        gl_lds16(Bb + (size_t)row * ldb + p * 8, Bs + c * 8);
    }
    __syncthreads();

    for (int t = 0; t < NT; ++t) {
        const int cur = t & 1;
        if (t + 1 < NT) {
            const int k0 = (t + 1) << 6;
            #pragma unroll
            for (int q = 0; q < 2; ++q) {
                const int c = q * 256 + tid, row = c >> 3, p = (c & 7) ^ (row & 7);
                gl_lds16(Ab + (size_t)row * lda + k0 + p * 8, As + (cur ^ 1) * 4096 + c * 8);
            }
            #pragma unroll
            for (int q = 0; q < 4; ++q) {
                const int c = q * 256 + tid, row = c >> 3, p = (c & 7) ^ (row & 7);
                gl_lds16(Bb + (size_t)row * ldb + k0 + p * 8, Bs + (cur ^ 1) * 8192 + c * 8);
            }
        }
        #pragma unroll
        for (int kk = 0; kk < 2; ++kk) {
            bf16x8 af[2], bv[4];
            #pragma unroll
            for (int mt = 0; mt < 2; ++mt) {
                const int row = wr * 32 + mt * 16 + lr;
                const int pc = (kk * 4 + lk) ^ (row & 7);
                af[mt] = *(const bf16x8*)(As + cur * 4096 + row * 64 + pc * 8);
            }
            #pragma unroll
            for (int nt = 0; nt < 4; ++nt) {
                const int col = wc * 64 + nt * 16 + lr;
                const int pc = (kk * 4 + lk) ^ (col & 7);
                bv[nt] = *(const bf16x8*)(Bs + cur * 8192 + col * 64 + pc * 8);
            }
            #pragma unroll
            for (int mt = 0; mt < 2; ++mt)
                #pragma unroll
                for (int nt = 0; nt < 4; ++nt)
                    acc[mt][nt] = mfma16(af[mt], bv[nt], acc[mt][nt]);
        }
        __syncthreads();
    }

    #pragma unroll
    for (int mt = 0; mt < 2; ++mt) {
        #pragma unroll
        for (int nt = 0; nt < 4; ++nt) {
            const int col = n0 + wc * 64 + nt * 16 + lr;
            const float bvv = J.bias ? J.bias[col] : 0.f;
            #pragma unroll
            for (int r = 0; r < 4; ++r) {
                const int row = m0 + wr * 32 + mt * 16 + lk * 4 + r;
                float v = acc[mt][nt][r] + bvv;
                if (J.relu) v = fmaxf(v, 0.f);
                if (J.C)  J.C[(size_t)row * J.ldc + col] = v;
                if (J.Cb) J.Cb[(size_t)row * J.ldc + col] = f2b(v);
            }
        }
    }
}

__global__ __launch_bounds__(256)
void gemm_tn4(GemmJob j0, GemmJob j1, GemmJob j2, GemmJob j3)
{
    __shared__ __align__(16) char smem[49152];
    int bid = blockIdx.x;
    if (bid < j0.nb) { gemm_body(j0, bid, smem); return; }
    bid -= j0.nb;
    if (bid < j1.nb) { gemm_body(j1, bid, smem); return; }
    bid -= j1.nb;
    if (bid < j2.nb) { gemm_body(j2, bid, smem); return; }
    bid -= j2.nb;
    gemm_body(j3, bid, smem);
}

// ---------------------------------------------------------------------------
// proj_pack: [0,nb0+nb1) projection GEMMs; then ffn weight transposes
// ---------------------------------------------------------------------------
__global__ __launch_bounds__(256)
void proj_pack_kernel(GemmJob j0, GemmJob j1,
                      const float* w1, const float* w2,
                      unsigned short* W1t, unsigned short* W2t)
{
    __shared__ __align__(16) char smem[49152];
    int bid = blockIdx.x;
    if (bid < j0.nb) { gemm_body(j0, bid, smem); return; }
    bid -= j0.nb;
    if (bid < j1.nb) { gemm_body(j1, bid, smem); return; }
    const int t = bid - j1.nb;
    if (t < 768) transpose_tile(w1, W1t, 1536, 2048, t, smem);
    else transpose_tile(w2, W2t, 2048, 768, t - 768, smem);
}

// ---------------------------------------------------------------------------
// mid3: [0,216) VWe GEMM; [216,432) VWn GEMM; [432,624) S2e+T; [624,816) S2n
// S2 written TRANSPOSED: S2[n][h][l][q] (q fastest) for coalesced softmax
// ---------------------------------------------------------------------------
__global__ __launch_bounds__(256)
void mid3_kernel(const unsigned short* __restrict__ QCb,
                 const unsigned short* __restrict__ LCb,
                 const unsigned short* __restrict__ Wet,
                 const unsigned short* __restrict__ Wot,
                 const float* __restrict__ e_bq,
                 unsigned short* __restrict__ VWe,
                 unsigned short* __restrict__ VWn,
                 float* __restrict__ S2e, float* __restrict__ Tb,
                 float* __restrict__ S2n)
{
    __shared__ __align__(16) union USm {
        struct { unsigned short As[8192], Bs[8192]; } g;
        unsigned short Ct[128 * 136];
        struct { float sA[52][65], sB[24][65]; } s;
    } U;
    const int bid = blockIdx.x;
    const int tid = threadIdx.x;

    if (bid < 432) {
        const int sub = bid >= 216;
        const int b = sub ? bid - 216 : bid;
        const int aoff = sub ? 2304 : 768;
        const unsigned short* Bt = sub ? Wot : Wet;
        unsigned short* Vout = sub ? VWn : VWe;

        const int h = b / 18, rm = b % 18, mt = rm / 6, ntile = rm % 6;
        const int m0 = mt * 128, n0 = ntile * 128;
        const int lane = tid & 63, w = tid >> 6, wr = w >> 1, wc = w & 1;
        const int lr = lane & 15, lk = lane >> 4;
        #pragma unroll
        for (int q = 0; q < 4; ++q) {
            const int c = q * 256 + tid, row = c >> 3, p = (c & 7) ^ (row & 7);
            gl_lds16(LCb + (size_t)(m0 + row) * 3072 + aoff + h * 64 + p * 8, &U.g.As[c * 8]);
            gl_lds16(Bt + (size_t)(n0 + row) * 768 + h * 64 + p * 8, &U.g.Bs[c * 8]);
        }
        __syncthreads();
        f32x4 acc[4][4] = {};
        #pragma unroll
        for (int kk = 0; kk < 2; ++kk) {
            bf16x8 af[4], bv[4];
            #pragma unroll
            for (int m2 = 0; m2 < 4; ++m2) {
                const int row = wr * 64 + m2 * 16 + lr;
                const int pc = (kk * 4 + lk) ^ (row & 7);
                af[m2] = *(const bf16x8*)&U.g.As[row * 64 + pc * 8];
            }
            #pragma unroll
            for (int n2 = 0; n2 < 4; ++n2) {
                const int col = wc * 64 + n2 * 16 + lr;
                const int pc = (kk * 4 + lk) ^ (col & 7);
                bv[n2] = *(const bf16x8*)&U.g.Bs[col * 64 + pc * 8];
            }
            #pragma unroll
            for (int m2 = 0; m2 < 4; ++m2)
                #pragma unroll
                for (int n2 = 0; n2 < 4; ++n2)
                    acc[m2][n2] = mfma16(af[m2], bv[n2], acc[m2][n2]);
        }
        __syncthreads();
        #pragma unroll
        for (int m2 = 0; m2 < 4; ++m2)
            #pragma unroll
            for (int n2 = 0; n2 < 4; ++n2) {
                const int col = wc * 64 + n2 * 16 + lr;
                #pragma unroll
                for (int r = 0; r < 4; ++r) {
                    const int row = wr * 64 + m2 * 16 + lk * 4 + r;
                    U.Ct[row * 136 + col] = f2b(acc[m2][n2][r]);
                }
            }
        __syncthreads();
        #pragma unroll
        for (int q = 0; q < 8; ++q) {
            const int item = q * 256 + tid;
            const int dl = item & 127, kg = item >> 7;
            const int m = m0 + kg * 8;
            const int nn = m / 24, l0 = m % 24;
            const int kc = (h * 24 + l0) >> 3;
            const int ks = kc >> 2;
            const int dg = n0 + dl;
            const int kpos = (kc & 3) ^ ((dg >> 1) & 3);
            u32x4 uu;
            #pragma unroll
            for (int e = 0; e < 4; ++e)
                uu[e] = (unsigned int)U.Ct[(kg * 8 + 2 * e) * 136 + dl]
                      | ((unsigned int)U.Ct[(kg * 8 + 2 * e + 1) * 136 + dl] << 16);
            *(u32x4*)(Vout + (size_t)nn * 221184 + ks * 24576 + dg * 32 + kpos * 8) = uu;
        }
    } else {
        const int sub = bid >= 624;               // 0: S2e(+T), 1: S2n
        const int b = bid - (sub ? 624 : 432);
        const int n = b / NHEAD, h = b % NHEAD;
        const int qoff = sub ? 768 : 0, koff = sub ? 1536 : 0;
        float* Sout = sub ? S2n : S2e;
        for (int p = tid; p < 52 * 64; p += 256) {
            const int q = p >> 6, d = p & 63;
            U.s.sA[q][d] = b2f(QCb[(size_t)(n * 52 + q) * 1536 + qoff + h * 64 + d]);
        }
        for (int p = tid; p < 24 * 64; p += 256) {
            const int l = p >> 6, d = p & 63;
            U.s.sB[l][d] = b2f(LCb[(size_t)(n * 24 + l) * 3072 + koff + h * 64 + d]);
        }
        __syncthreads();
        for (int p = tid; p < 52 * 24; p += 256) {
            const int l = p / 52, q = p % 52;       // transposed: l slow, q fast
            float s = 0.f;
            #pragma unroll
            for (int d = 0; d < 64; ++d) s += U.s.sA[q][d] * U.s.sB[l][d];
            Sout[((size_t)(n * NHEAD + h) * 24 + l) * 52 + q] = s;
        }
        if (!sub && tid < 24) {
            float s = 0.f;
            #pragma unroll
            for (int d = 0; d < 64; ++d) s += e_bq[h * 64 + d] * U.s.sB[tid][d];
            Tb[((size_t)n * NHEAD + h) * 24 + tid] = s;
        }
    }
}

// ---------------------------------------------------------------------------
// attn_kernel v4b: full-width blocks (round-12) + true softmax/B-fetch overlap.
// Both B stages pre-issued; pre-softmax barrier is lgkmcnt-only (raw s_barrier)
// so the 96 KB of B loads stay in flight across the softmax VALU phase. The
// post-softmax __syncthreads (vmcnt0) finds them arrived. Loop issues ks+1
// only for ks>=1.
// [0,416): edge, block = (n, i-pair), 512 thr / 8 waves (2 i x 4 cg of 192).
// [416,432): node, block = (n).
// ---------------------------------------------------------------------------
__global__ __launch_bounds__(512)
void attn_kernel(const float* __restrict__ S2e, const float* __restrict__ Tb,
                 const float* __restrict__ S2n, const int* __restrict__ co_mask,
                 const unsigned short* __restrict__ VWe,
                 const unsigned short* __restrict__ VWn,
                 const float* __restrict__ ebo, const float* __restrict__ nbo,
                 unsigned short* __restrict__ EdgeBb,
                 unsigned short* __restrict__ NodePb)
{
    __shared__ __align__(16) char smem[161760];
    unsigned short* Pf = (unsigned short*)smem;              // [2][52*288] = 59904 B
    unsigned short* Bs = (unsigned short*)(smem + 59904);    // 2 x 24576 shorts = 98304 B
    float* SiT = (float*)(smem + 158208);                    // [2][288] = 2304 B
    unsigned char* cmb = (unsigned char*)(smem + 160512);    // 1248 B
    const int bid = blockIdx.x;
    const int tid = threadIdx.x;
    const int lane = tid & 63, w = tid >> 6;
    const int lr = lane & 15, lk = lane >> 4;

    if (bid < 416) {
        const int sw = (bid & 7) * 52 + (bid >> 3);          // XCD-contiguous n
        const int n = sw / 26;
        const int ip = sw % 26;
        const int i0 = ip * 2;
        const unsigned short* Bsrc = VWe + (size_t)n * 221184;
        const float* S2x = S2e + (size_t)n * NHEAD * 24 * 52;   // [h][l][j]

        // pre-issue B stages 0 AND 1 (stay in flight across softmax)
        #pragma unroll
        for (int s = 0; s < 2; ++s) {
            const unsigned short* src = Bsrc + (size_t)s * 24576;
            unsigned short* dstb = Bs + s * 24576;
            #pragma unroll
            for (int q = 0; q < 6; ++q) {
                const int c = q * 512 + tid;
                gl_lds16(src + c * 8, dstb + c * 8);
            }
        }
        for (int p = tid; p < 576; p += 512) {
            const int ii = p >= 288 ? 1 : 0;
            const int rl = p - ii * 288;                     // h*24 + l
            SiT[ii * 288 + rl] = S2x[(size_t)rl * 52 + i0 + ii]
                               + Tb[(size_t)n * 288 + rl];
        }
        for (int p = tid; p < 1248; p += 512)
            cmb[p] = (unsigned char)(co_mask[(size_t)n * 1248 + p] > 0);
        // lgkm-only barrier: orders SiT/cmb LDS writes, leaves B vmem in flight
        asm volatile("s_waitcnt lgkmcnt(0)" ::: "memory");
        __builtin_amdgcn_sched_barrier(0);
        __builtin_amdgcn_s_barrier();
        __builtin_amdgcn_sched_barrier(0);

        // softmax rows (ii,h,j) -> Pf[ii], swizzled chunk layout — ONCE
        for (int p = tid; p < 1248; p += 512) {
            const int ii = p >= 624 ? 1 : 0;
            const int rl = p - ii * 624;
            const int h = rl / 52, j = rl % 52;
            const float* Sc = S2x + (size_t)h * 1248 + j;    // stride 52 over l
            const float* st = SiT + ii * 288 + h * 24;
            float x[24]; float mx = -1e30f;
            #pragma unroll
            for (int l = 0; l < 24; ++l) {
                float v = (st[l] - Sc[l * 52]) * 0.125f;
                v = cmb[l * 52 + j] ? v : -1e9f;
                x[l] = v; mx = fmaxf(mx, v);
            }
            float sum = 0.f;
            #pragma unroll
            for (int l = 0; l < 24; ++l) { const float e = __expf(x[l] - mx); x[l] = e; sum += e; }
            const float inv = 1.f / sum;
            unsigned short* Prow = Pf + ii * 14976 + j * 288;
            const int swk = (j >> 1) & 3;
            #pragma unroll
            for (int c = 0; c < 3; ++c) {
                u32x4 u;
                #pragma unroll
                for (int m = 0; m < 4; ++m)
                    u[m] = pack2(x[c * 8 + 2 * m] * inv, x[c * 8 + 2 * m + 1] * inv);
                *(u32x4*)(Prow + (((3 * h + c) ^ swk) << 3)) = u;
            }
        }
        __syncthreads();                                     // drains vmcnt: stages 0,1 ready

        const int iw = w >> 2, cg = (w & 3) * 192;
        f32x4 acc[4][12] = {};
        for (int ks = 0; ks < 9; ++ks) {
            const int cur = ks & 1;
            if (ks >= 1 && ks < 8) {
                const unsigned short* src = Bsrc + (size_t)(ks + 1) * 24576;
                #pragma unroll
                for (int q = 0; q < 6; ++q) {
                    const int c = q * 512 + tid;
                    gl_lds16(src + c * 8, Bs + (cur ^ 1) * 24576 + c * 8);
                }
            }
            bf16x8 af[4];
            #pragma unroll
            for (int mt = 0; mt < 4; ++mt) {
                const int row = mt * 16 + lr;
                const int rowc = row < NOBJ ? row : 0;       // clamp pad rows
                af[mt] = *(const bf16x8*)(Pf + iw * 14976 + rowc * 288
                                          + (((ks * 4 + lk) ^ ((rowc >> 1) & 3)) << 3));
            }
            #pragma unroll
            for (int nt = 0; nt < 12; ++nt) {
                const int cl = cg + nt * 16 + lr;
                bf16x8 bv = *(const bf16x8*)(Bs + cur * 24576 + cl * 32
                                             + ((lk ^ ((cl >> 1) & 3)) << 3));
                #pragma unroll
                for (int mt = 0; mt < 4; ++mt)
                    acc[mt][nt] = mfma16(af[mt], bv, acc[mt][nt]);
            }
            __syncthreads();
        }

        #pragma unroll
        for (int nt = 0; nt < 12; ++nt) {
            float m = -1e30f;
            #pragma unroll
            for (int mt = 0; mt < 4; ++mt)
                #pragma unroll
                for (int r = 0; r < 4; ++r) {
                    const int row = mt * 16 + lk * 4 + r;
                    if (row < NOBJ) m = fmaxf(m, acc[mt][nt][r]);
                }
            m = fmaxf(m, __shfl_xor(m, 16));
            m = fmaxf(m, __shfl_xor(m, 32));
            if (lk == 0) {
                const int col = cg + nt * 16 + lr;
                EdgeBb[(size_t)(n * 52 + i0 + iw) * 768 + col] = f2b(m + ebo[col]);
            }
        }
    } else {
        const int n = bid - 416;
        const unsigned short* Bsrc = VWn + (size_t)n * 221184;
        const float* S2x = S2n + (size_t)n * NHEAD * 24 * 52;   // [h][l][j]

        #pragma unroll
        for (int s = 0; s < 2; ++s) {
            const unsigned short* src = Bsrc + (size_t)s * 24576;
            unsigned short* dstb = Bs + s * 24576;
            #pragma unroll
            for (int q = 0; q < 6; ++q) {
                const int c = q * 512 + tid;
                gl_lds16(src + c * 8, dstb + c * 8);
            }
        }
        for (int p = tid; p < 1248; p += 512)
            cmb[p] = (unsigned char)(co_mask[(size_t)n * 1248 + p] > 0);
        asm volatile("s_waitcnt lgkmcnt(0)" ::: "memory");
        __builtin_amdgcn_sched_barrier(0);
        __builtin_amdgcn_s_barrier();
        __builtin_amdgcn_sched_barrier(0);

        for (int p = tid; p < 624; p += 512) {
            const int h = p / 52, q = p % 52;
            const float* Sc = S2x + (size_t)h * 1248 + q;
            float x[24]; float mx = -1e30f;
            #pragma unroll
            for (int l = 0; l < 24; ++l) {
                float v = Sc[l * 52] * 0.125f;
                v = cmb[l * 52 + q] ? v : -1e9f;
                x[l] = v; mx = fmaxf(mx, v);
            }
            float sum = 0.f;
            #pragma unroll
            for (int l = 0; l < 24; ++l) { const float e = __expf(x[l] - mx); x[l] = e; sum += e; }
            const float inv = 1.f / sum;
            unsigned short* Prow = Pf + q * 288;
            const int swk = (q >> 1) & 3;
            #pragma unroll
            for (int c = 0; c < 3; ++c) {
                u32x4 u;
                #pragma unroll
                for (int m = 0; m < 4; ++m)
                    u[m] = pack2(x[c * 8 + 2 * m] * inv, x[c * 8 + 2 * m + 1] * inv);
                *(u32x4*)(Prow + (((3 * h + c) ^ swk) << 3)) = u;
            }
        }
        __syncthreads();

        const int cg = w * 96;
        f32x4 acc[4][6] = {};
        for (int ks = 0; ks < 9; ++ks) {
            const int cur = ks & 1;
            if (ks >= 1 && ks < 8) {
                const unsigned short* src = Bsrc + (size_t)(ks + 1) * 24576;
                #pragma unroll
                for (int q = 0; q < 6; ++q) {
                    const int c = q * 512 + tid;
                    gl_lds16(src + c * 8, Bs + (cur ^ 1) * 24576 + c * 8);
                }
            }
            bf16x8 af[4];
            #pragma unroll
            for (int mt = 0; mt < 4; ++mt) {
                const int row = mt * 16 + lr;
                const int rowc = row < NOBJ ? row : 0;
                af[mt] = *(const bf16x8*)(Pf + rowc * 288
                                          + (((ks * 4 + lk) ^ ((rowc >> 1) & 3)) << 3));
            }
            #pragma unroll
            for (int nt = 0; nt < 6; ++nt) {
                const int cl = cg + nt * 16 + lr;
                bf16x8 bv = *(const bf16x8*)(Bs + cur * 24576 + cl * 32
                                             + ((lk ^ ((cl >> 1) & 3)) << 3));
                #pragma unroll
                for (int mt = 0; mt < 4; ++mt)
                    acc[mt][nt] = mfma16(af[mt], bv, acc[mt][nt]);
            }
            __syncthreads();
        }

        #pragma unroll
        for (int nt = 0; nt < 6; ++nt) {
            const int col = cg + nt * 16 + lr;
            const float bv = nbo[col];
            #pragma unroll
            for (int mt = 0; mt < 4; ++mt)
                #pragma unroll
                for (int r = 0; r < 4; ++r) {
                    const int row = mt * 16 + lk * 4 + r;
                    if (row < NOBJ)
                        NodePb[(size_t)(n * 52 + row) * 768 + col] = f2b(acc[mt][nt][r] + bv);
                }
        }
    }
}

// ---------------------------------------------------------------------------
// ln_dual: rows 0..831 -> LN(obj+NodePb); rows 832..1663 -> LN(obj+EdgeBb)
// ---------------------------------------------------------------------------
__global__ __launch_bounds__(256)
void ln_dual_kernel(const float* __restrict__ obj,
                    const unsigned short* __restrict__ NodePb,
                    const unsigned short* __restrict__ EdgeBb,
                    const float* __restrict__ gq, const float* __restrict__ bq,
                    const float* __restrict__ ge, const float* __restrict__ be,
                    unsigned short* __restrict__ Fusedb)
{
    __shared__ float red[8];
    const int job = blockIdx.x >= 832;
    const int row = blockIdx.x - (job ? 832 : 0);
    const int tid = threadIdx.x;
    const unsigned short* x2 = (job ? EdgeBb : NodePb) + (size_t)row * 768;
    const float* x1 = obj + (size_t)row * 768;
    const float* g = job ? ge : gq;
    const float* bb = job ? be : bq;
    float v[3]; float s = 0.f;
    #pragma unroll
    for (int c = 0; c < 3; ++c) {
        const int col = tid + 256 * c;
        v[c] = x1[col] + b2f(x2[col]); s += v[c];
    }
    #pragma unroll
    for (int o = 32; o; o >>= 1) s += __shfl_xor(s, o);
    if ((tid & 63) == 0) red[tid >> 6] = s;
    __syncthreads();
    const float mean = (red[0] + red[1] + red[2] + red[3]) * (1.f / 768.f);
    float var = 0.f;
    #pragma unroll
    for (int c = 0; c < 3; ++c) { const float d = v[c] - mean; var += d * d; }
    #pragma unroll
    for (int o = 32; o; o >>= 1) var += __shfl_xor(var, o);
    __syncthreads();
    if ((tid & 63) == 0) red[4 + (tid >> 6)] = var;
    __syncthreads();
    const float vt = (red[4] + red[5] + red[6] + red[7]) * (1.f / 768.f);
    const float rs = rsqrtf(vt + 1e-5f);
    unsigned short* dst = Fusedb + (size_t)row * 1536 + (job ? 768 : 0);
    #pragma unroll
    for (int c = 0; c < 3; ++c) {
        const int col = tid + 256 * c;
        dst[col] = f2b((v[c] - mean) * rs * g[col] + bb[col]);
    }
}

// ---------------------------------------------------------------------------
// final LN: out = LN(Fusedb + sum of 4 ffn2 K-partials + ffn_b2)
// ---------------------------------------------------------------------------
__global__ __launch_bounds__(256)
void ln2_kernel(const unsigned short* __restrict__ x1b,
                const float* __restrict__ Hp, const float* __restrict__ b2,
                const float* __restrict__ g, const float* __restrict__ bb,
                float* __restrict__ dst)
{
    __shared__ float red[8];
    const int row = blockIdx.x, tid = threadIdx.x;
    float v[3]; float s = 0.f;
    #pragma unroll
    for (int c = 0; c < 3; ++c) {
        const int col = tid + 256 * c;
        const size_t o = (size_t)row * 768 + col;
        float h = Hp[o] + Hp[638976 + o] + Hp[2 * 638976 + o] + Hp[3 * 638976 + o];
        v[c] = b2f(x1b[(size_t)row * 1536 + col]) + h + b2[col];
        s += v[c];
    }
    #pragma unroll
    for (int o = 32; o; o >>= 1) s += __shfl_xor(s, o);
    if ((tid & 63) == 0) red[tid >> 6] = s;
    __syncthreads();
    const float mean = (red[0] + red[1] + red[2] + red[3]) * (1.f / 768.f);
    float var = 0.f;
    #pragma unroll
    for (int c = 0; c < 3; ++c) { const float d = v[c] - mean; var += d * d; }
    #pragma unroll
    for (int o = 32; o; o >>= 1) var += __shfl_xor(var, o);
    __syncthreads();
    if ((tid & 63) == 0) red[4 + (tid >> 6)] = var;
    __syncthreads();
    const float vt = (red[4] + red[5] + red[6] + red[7]) * (1.f / 768.f);
    const float rs = rsqrtf(vt + 1e-5f);
    #pragma unroll
    for (int c = 0; c < 3; ++c) {
        const int col = tid + 256 * c;
        dst[(size_t)row * 768 + col] = (v[c] - mean) * rs * g[col] + bb[col];
    }
}

// ---------------------------------------------------------------------------
extern "C" void kernel_launch(void* const* d_in, const int* in_sizes, int n_in,
                              void* d_out, int out_size, void* d_ws, size_t ws_size,
                              hipStream_t stream)
{
    (void)in_sizes; (void)n_in; (void)out_size; (void)ws_size;
    const float* lang  = (const float*)d_in[0];
    const float* obj   = (const float*)d_in[1];
    const int* co_mask = (const int*)d_in[4];
    const float* e_wq = (const float*)d_in[5];
    const float* e_bq = (const float*)d_in[6];
    const float* e_wk = (const float*)d_in[7];
    const float* e_bk = (const float*)d_in[8];
    const float* e_wv = (const float*)d_in[9];
    const float* e_bv = (const float*)d_in[10];
    const float* e_wo = (const float*)d_in[11];
    const float* e_bo = (const float*)d_in[12];
    const float* n_wq = (const float*)d_in[13];
    const float* n_bq = (const float*)d_in[14];
    const float* n_wk = (const float*)d_in[15];
    const float* n_bk = (const float*)d_in[16];
    const float* n_wv = (const float*)d_in[17];
    const float* n_bv = (const float*)d_in[18];
    const float* n_wo = (const float*)d_in[19];
    const float* n_bo = (const float*)d_in[20];
    const float* ffn_w1 = (const float*)d_in[21];
    const float* ffn_b1 = (const float*)d_in[22];
    const float* ffn_w2 = (const float*)d_in[23];
    const float* ffn_b2 = (const float*)d_in[24];
    const float* ln_e_g = (const float*)d_in[25];
    const float* ln_e_b = (const float*)d_in[26];
    const float* ln_q_g = (const float*)d_in[27];
    const float* ln_q_b = (const float*)d_in[28];
    const float* ln2_g = (const float*)d_in[29];
    const float* ln2_b = (const float*)d_in[30];
    float* out = (float*)d_out;

    // ---- workspace layout (flat, ~60 MB of ~256 MB) ----
    char* wsb = (char*)d_ws;
    unsigned short* Wqt   = (unsigned short*)(wsb + 0);          // [1536][768]
    unsigned short* Wlt   = (unsigned short*)(wsb + 2359296);    // [3072][768]
    unsigned short* Wet   = (unsigned short*)(wsb + 7077888);    // [768][768]
    unsigned short* Wot   = (unsigned short*)(wsb + 8257536);    // [768][768]
    unsigned short* W1t   = (unsigned short*)(wsb + 9437184);    // [2048][1536]
    unsigned short* W2t   = (unsigned short*)(wsb + 15728640);   // [768][2048]
    unsigned short* objb  = (unsigned short*)(wsb + 18874368);   // [832][768]
    unsigned short* langb = (unsigned short*)(wsb + 20152320);   // [384][768]
    float*          bqc   = (float*)(wsb + 20742144);            // [1536]
    float*          blc   = (float*)(wsb + 20748288);            // [3072]
    unsigned short* QCb   = (unsigned short*)(wsb + 20760576);   // [832][1536]
    unsigned short* LCb   = (unsigned short*)(wsb + 23316480);   // [384][3072]
    float*          S2e   = (float*)(wsb + 25675776);            // [16][12][24][52]
    float*          Tb    = (float*)(wsb + 26634240);            // [16][12][24]
    float*          S2n   = (float*)(wsb + 26652672);            // [16][12][24][52]
    unsigned short* VWe   = (unsigned short*)(wsb + 27611136);   // 16*221184
    unsigned short* VWn   = (unsigned short*)(wsb + 34689024);   // 16*221184
    unsigned short* NodePb= (unsigned short*)(wsb + 41766912);   // [832][768]
    unsigned short* EdgeBb= (unsigned short*)(wsb + 43044864);   // [832][768]
    unsigned short* Fusedb= (unsigned short*)(wsb + 44322816);   // [832][1536]
    unsigned short* H1b   = (unsigned short*)(wsb + 46878720);   // [832][2048]
    float*          Hp    = (float*)(wsb + 50286592);            // 4x[832][768] f32

    dim3 blk(256);
    // L1: pack square weights + activations + fused biases
    pack1_kernel<<<2069, blk, 0, stream>>>(
        e_wq, n_wq, e_wk, e_wv, n_wk, n_wv, n_wo, e_wo,
        Wqt, Wqt + 589824, Wlt, Wlt + 589824, Wlt + 2 * 589824, Wlt + 3 * 589824,
        Wot, Wet,
        obj, lang, n_bq, e_bk, e_bv, n_bk, n_bv, objb, langb, bqc, blc);
    // L2: both input projections + FFN weight transposes (independent filler)
    {
        GemmJob p0 = {objb, Wqt, bqc, nullptr, QCb, 768, 768, 1536, 768, 12, 156, 0, 0};
        GemmJob p1 = {langb, Wlt, blc, nullptr, LCb, 768, 768, 3072, 768, 24, 144, 0, 0};
        proj_pack_kernel<<<1452, blk, 0, stream>>>(p0, p1, ffn_w1, ffn_w2, W1t, W2t);
    }
    // L3: VWe + VWn (MFMA) + S2e/T + S2n (transposed S2 layout)
    mid3_kernel<<<816, blk, 0, stream>>>(QCb, LCb, Wet, Wot, e_bq,
                                         VWe, VWn, S2e, Tb, S2n);
    // L4: fused softmax + A@VW (edge 416 full-width + node 16)
    attn_kernel<<<432, dim3(512), 0, stream>>>(S2e, Tb, S2n, co_mask, VWe, VWn,
                                               e_bo, n_bo, EdgeBb, NodePb);
    // L5: both fuse layernorms
    ln_dual_kernel<<<1664, blk, 0, stream>>>(obj, NodePb, EdgeBb, ln_q_g, ln_q_b,
                                             ln_e_g, ln_e_b, Fusedb);
    // L6: FFN1
    {
        GemmJob p0 = {Fusedb, W1t, ffn_b1, nullptr, H1b, 1536, 1536, 2048, 1536, 16, 208, 1, 1};
        gemm_tn4<<<208, blk, 0, stream>>>(p0, p0, p0, p0);
    }
    // L7: FFN2 K-split x4 -> f32 partials
    {
        GemmJob q0 = {H1b,        W2t,        nullptr, Hp,               nullptr, 2048, 2048, 768, 512, 6, 78, 0, 0};
        GemmJob q1 = {H1b + 512,  W2t + 512,  nullptr, Hp + 638976,      nullptr, 2048, 2048, 768, 512, 6, 78, 0, 0};
        GemmJob q2 = {H1b + 1024, W2t + 1024, nullptr, Hp + 2 * 638976,  nullptr, 2048, 2048, 768, 512, 6, 78, 0, 0};
        GemmJob q3 = {H1b + 1536, W2t + 1536, nullptr, Hp + 3 * 638976,  nullptr, 2048, 2048, 768, 512, 6, 78, 0, 0};
        gemm_tn4<<<312, blk, 0, stream>>>(q0, q1, q2, q3);
    }
    // L8: final LN (sums partials + bias)
    ln2_kernel<<<832, blk, 0, stream>>>(Fusedb, Hp, ffn_b2, ln2_g, ln2_b, out);
}

// Round 16
// 123.213 us; speedup vs baseline: 1.0351x; 1.0011x over previous
//
#include <hip/hip_runtime.h>
#include <math.h>

#define NOBJ 52
#define LL 24
#define NHEAD 12

typedef __attribute__((ext_vector_type(8))) short bf16x8;
typedef __attribute__((ext_vector_type(4))) float f32x4;
typedef __attribute__((ext_vector_type(4))) unsigned int u32x4;
typedef __attribute__((ext_vector_type(2))) unsigned int u32x2;

__device__ __forceinline__ unsigned short f2b(float x) {
    union { float f; unsigned int u; } v; v.f = x;
    unsigned int r = v.u + 0x7fffu + ((v.u >> 16) & 1u);
    return (unsigned short)(r >> 16);
}
__device__ __forceinline__ float b2f(unsigned short u) {
    union { unsigned int u; float f; } v; v.u = ((unsigned int)u) << 16;
    return v.f;
}
__device__ __forceinline__ unsigned int pack2(float a, float b) {
    return (unsigned int)f2b(a) | ((unsigned int)f2b(b) << 16);
}
__device__ __forceinline__ f32x4 mfma16(bf16x8 a, bf16x8 b, f32x4 c) {
    return __builtin_amdgcn_mfma_f32_16x16x32_bf16(a, b, c, 0, 0, 0);
}
__device__ __forceinline__ void gl_lds16(const void* g, void* lds) {
    __builtin_amdgcn_global_load_lds(
        (const __attribute__((address_space(1))) unsigned int*)g,
        (__attribute__((address_space(3))) unsigned int*)lds, 16, 0, 0);
}

// ---------------------------------------------------------------------------
// 64x64 transpose tile: f32 [K][N] -> bf16 [N][K]
// ---------------------------------------------------------------------------
__device__ __forceinline__ void transpose_tile(const float* __restrict__ src,
    unsigned short* __restrict__ dst, int K, int N, int t, char* smem)
{
    float (*ts)[65] = (float(*)[65])smem;
    const int tid = threadIdx.x;
    const int ntk = K >> 6;
    const int k0 = (t % ntk) << 6, n0 = (t / ntk) << 6;
    const int tx = tid & 63, ty = tid >> 6;
    #pragma unroll
    for (int i2 = 0; i2 < 16; ++i2) {
        const int row = i2 * 4 + ty;
        ts[row][tx] = src[(size_t)(k0 + row) * N + n0 + tx];
    }
    __syncthreads();
    #pragma unroll
    for (int i2 = 0; i2 < 16; ++i2) {
        const int row = i2 * 4 + ty;
        dst[(size_t)(n0 + row) * K + k0 + tx] = f2b(ts[tx][row]);
    }
}

// ---------------------------------------------------------------------------
// pack1: 8 square weight transposes [0,1152) + activation/bias pack [1152,...)
// ---------------------------------------------------------------------------
__global__ __launch_bounds__(256)
void pack1_kernel(const float* s0, const float* s1, const float* s2,
                  const float* s3, const float* s4, const float* s5,
                  const float* s6, const float* s7,
                  unsigned short* d0, unsigned short* d1, unsigned short* d2,
                  unsigned short* d3, unsigned short* d4, unsigned short* d5,
                  unsigned short* d6, unsigned short* d7,
                  const float* obj, const float* lang, const float* n_bq,
                  const float* e_bk, const float* e_bv,
                  const float* n_bk, const float* n_bv,
                  unsigned short* objb, unsigned short* langb,
                  float* bqc, float* blc)
{
    __shared__ __align__(16) char smem[16640];
    const int bid = blockIdx.x;
    const int tid = threadIdx.x;
    if (bid < 1152) {
        const int job = bid / 144, t = bid % 144;
        const float* src; unsigned short* dst;
        switch (job) {
            case 0: src = s0; dst = d0; break;
            case 1: src = s1; dst = d1; break;
            case 2: src = s2; dst = d2; break;
            case 3: src = s3; dst = d3; break;
            case 4: src = s4; dst = d4; break;
            case 5: src = s5; dst = d5; break;
            case 6: src = s6; dst = d6; break;
            default: src = s7; dst = d7; break;
        }
        transpose_tile(src, dst, 768, 768, t, smem);
    } else {
        const int base = ((bid - 1152) * 256 + tid) * 4;
        const int T0 = 638976, T1 = 933888, T2 = 935424, T3 = 938496;
        if (base >= T3) return;
        if (base < T0) {
            f32x4 v = *(const f32x4*)(obj + base);
            *(u32x2*)(objb + base) = (u32x2){pack2(v[0], v[1]), pack2(v[2], v[3])};
        } else if (base < T1) {
            const int j = base - T0;
            f32x4 v = *(const f32x4*)(lang + j);
            *(u32x2*)(langb + j) = (u32x2){pack2(v[0], v[1]), pack2(v[2], v[3])};
        } else if (base < T2) {
            const int j = base - T1;
            if (j < 768) { *(f32x4*)(bqc + j) = (f32x4){0.f, 0.f, 0.f, 0.f}; }
            else         { *(f32x4*)(bqc + j) = *(const f32x4*)(n_bq + j - 768); }
        } else {
            const int j = base - T2;
            const int s = j / 768, c = j % 768;
            const float* p = (s == 0) ? e_bk : (s == 1) ? e_bv : (s == 2) ? n_bk : n_bv;
            *(f32x4*)(blc + j) = *(const f32x4*)(p + c);
        }
    }
}

// ---------------------------------------------------------------------------
// Generic GEMM: C[M,N] = A[M,K](bf16) @ Bt[N,K-slice]^T + bias (+relu).
// 64x128 tile, BK=64, dbuf global_load_lds, chunk-XOR swizzle. 256 thr.
// ---------------------------------------------------------------------------
struct GemmJob {
    const unsigned short* A; const unsigned short* Bt; const float* bias;
    float* C; unsigned short* Cb;
    int lda, ldb, ldc, K, nbx, nb, relu, swz;
};

__device__ __forceinline__ void gemm_body(const GemmJob J, int bid, char* smem)
{
    unsigned short* As = (unsigned short*)smem;             // 2 x 4096
    unsigned short* Bs = (unsigned short*)(smem + 16384);   // 2 x 8192
    int bx, by;
    if (J.swz) {
        const int cpx = J.nb >> 3;
        const int gid = (bid & 7) * cpx + (bid >> 3);
        const int nbm = J.nb / J.nbx;
        bx = gid / nbm; by = gid % nbm;
    } else { bx = bid % J.nbx; by = bid / J.nbx; }
    const int n0 = bx * 128, m0 = by * 64;
    const int tid = threadIdx.x;
    const int lane = tid & 63;
    const int w = tid >> 6, wr = w >> 1, wc = w & 1;
    const int lr = lane & 15, lk = lane >> 4;
    const int lda = J.lda, ldb = J.ldb, K = J.K;
    const unsigned short* Ab = J.A + (size_t)m0 * lda;
    const unsigned short* Bb = J.Bt + (size_t)n0 * ldb;

    f32x4 acc[2][4] = {};
    const int NT = K >> 6;

    #pragma unroll
    for (int q = 0; q < 2; ++q) {
        const int c = q * 256 + tid, row = c >> 3, p = (c & 7) ^ (row & 7);
        gl_lds16(Ab + (size_t)row * lda + p * 8, As + c * 8);
    }
    #pragma unroll
    for (int q = 0; q < 4; ++q) {
        const int c = q * 256 + tid, row = c >> 3, p = (c & 7) ^ (row & 7);
        gl_lds16(Bb + (size_t)row * ldb + p * 8, Bs + c * 8);
    }
    __syncthreads();

    for (int t = 0; t < NT; ++t) {
        const int cur = t & 1;
        if (t + 1 < NT) {
            const int k0 = (t + 1) << 6;
            #pragma unroll
            for (int q = 0; q < 2; ++q) {
                const int c = q * 256 + tid, row = c >> 3, p = (c & 7) ^ (row & 7);
                gl_lds16(Ab + (size_t)row * lda + k0 + p * 8, As + (cur ^ 1) * 4096 + c * 8);
            }
            #pragma unroll
            for (int q = 0; q < 4; ++q) {
                const int c = q * 256 + tid, row = c >> 3, p = (c & 7) ^ (row & 7);
                gl_lds16(Bb + (size_t)row * ldb + k0 + p * 8, Bs + (cur ^ 1) * 8192 + c * 8);
            }
        }
        #pragma unroll
        for (int kk = 0; kk < 2; ++kk) {
            bf16x8 af[2], bv[4];
            #pragma unroll
            for (int mt = 0; mt < 2; ++mt) {
                const int row = wr * 32 + mt * 16 + lr;
                const int pc = (kk * 4 + lk) ^ (row & 7);
                af[mt] = *(const bf16x8*)(As + cur * 4096 + row * 64 + pc * 8);
            }
            #pragma unroll
            for (int nt = 0; nt < 4; ++nt) {
                const int col = wc * 64 + nt * 16 + lr;
                const int pc = (kk * 4 + lk) ^ (col & 7);
                bv[nt] = *(const bf16x8*)(Bs + cur * 8192 + col * 64 + pc * 8);
            }
            #pragma unroll
            for (int mt = 0; mt < 2; ++mt)
                #pragma unroll
                for (int nt = 0; nt < 4; ++nt)
                    acc[mt][nt] = mfma16(af[mt], bv[nt], acc[mt][nt]);
        }
        __syncthreads();
    }

    #pragma unroll
    for (int mt = 0; mt < 2; ++mt) {
        #pragma unroll
        for (int nt = 0; nt < 4; ++nt) {
            const int col = n0 + wc * 64 + nt * 16 + lr;
            const float bvv = J.bias ? J.bias[col] : 0.f;
            #pragma unroll
            for (int r = 0; r < 4; ++r) {
                const int row = m0 + wr * 32 + mt * 16 + lk * 4 + r;
                float v = acc[mt][nt][r] + bvv;
                if (J.relu) v = fmaxf(v, 0.f);
                if (J.C)  J.C[(size_t)row * J.ldc + col] = v;
                if (J.Cb) J.Cb[(size_t)row * J.ldc + col] = f2b(v);
            }
        }
    }
}

__global__ __launch_bounds__(256)
void gemm_tn4(GemmJob j0, GemmJob j1, GemmJob j2, GemmJob j3)
{
    __shared__ __align__(16) char smem[49152];
    int bid = blockIdx.x;
    if (bid < j0.nb) { gemm_body(j0, bid, smem); return; }
    bid -= j0.nb;
    if (bid < j1.nb) { gemm_body(j1, bid, smem); return; }
    bid -= j1.nb;
    if (bid < j2.nb) { gemm_body(j2, bid, smem); return; }
    bid -= j2.nb;
    gemm_body(j3, bid, smem);
}

// ---------------------------------------------------------------------------
// proj_pack: [0,nb0+nb1) projection GEMMs; then ffn weight transposes
// ---------------------------------------------------------------------------
__global__ __launch_bounds__(256)
void proj_pack_kernel(GemmJob j0, GemmJob j1,
                      const float* w1, const float* w2,
                      unsigned short* W1t, unsigned short* W2t)
{
    __shared__ __align__(16) char smem[49152];
    int bid = blockIdx.x;
    if (bid < j0.nb) { gemm_body(j0, bid, smem); return; }
    bid -= j0.nb;
    if (bid < j1.nb) { gemm_body(j1, bid, smem); return; }
    const int t = bid - j1.nb;
    if (t < 768) transpose_tile(w1, W1t, 1536, 2048, t, smem);
    else transpose_tile(w2, W2t, 2048, 768, t - 768, smem);
}

// ---------------------------------------------------------------------------
// mid3: [0,216) VWe GEMM; [216,432) VWn GEMM; [432,624) S2e+T; [624,816) S2n
// S2 written TRANSPOSED: S2[n][h][l][q] (q fastest) for coalesced softmax
// ---------------------------------------------------------------------------
__global__ __launch_bounds__(256)
void mid3_kernel(const unsigned short* __restrict__ QCb,
                 const unsigned short* __restrict__ LCb,
                 const unsigned short* __restrict__ Wet,
                 const unsigned short* __restrict__ Wot,
                 const float* __restrict__ e_bq,
                 unsigned short* __restrict__ VWe,
                 unsigned short* __restrict__ VWn,
                 float* __restrict__ S2e, float* __restrict__ Tb,
                 float* __restrict__ S2n)
{
    __shared__ __align__(16) union USm {
        struct { unsigned short As[8192], Bs[8192]; } g;
        unsigned short Ct[128 * 136];
        struct { float sA[52][65], sB[24][65]; } s;
    } U;
    const int bid = blockIdx.x;
    const int tid = threadIdx.x;

    if (bid < 432) {
        const int sub = bid >= 216;
        const int b = sub ? bid - 216 : bid;
        const int aoff = sub ? 2304 : 768;
        const unsigned short* Bt = sub ? Wot : Wet;
        unsigned short* Vout = sub ? VWn : VWe;

        const int h = b / 18, rm = b % 18, mt = rm / 6, ntile = rm % 6;
        const int m0 = mt * 128, n0 = ntile * 128;
        const int lane = tid & 63, w = tid >> 6, wr = w >> 1, wc = w & 1;
        const int lr = lane & 15, lk = lane >> 4;
        #pragma unroll
        for (int q = 0; q < 4; ++q) {
            const int c = q * 256 + tid, row = c >> 3, p = (c & 7) ^ (row & 7);
            gl_lds16(LCb + (size_t)(m0 + row) * 3072 + aoff + h * 64 + p * 8, &U.g.As[c * 8]);
            gl_lds16(Bt + (size_t)(n0 + row) * 768 + h * 64 + p * 8, &U.g.Bs[c * 8]);
        }
        __syncthreads();
        f32x4 acc[4][4] = {};
        #pragma unroll
        for (int kk = 0; kk < 2; ++kk) {
            bf16x8 af[4], bv[4];
            #pragma unroll
            for (int m2 = 0; m2 < 4; ++m2) {
                const int row = wr * 64 + m2 * 16 + lr;
                const int pc = (kk * 4 + lk) ^ (row & 7);
                af[m2] = *(const bf16x8*)&U.g.As[row * 64 + pc * 8];
            }
            #pragma unroll
            for (int n2 = 0; n2 < 4; ++n2) {
                const int col = wc * 64 + n2 * 16 + lr;
                const int pc = (kk * 4 + lk) ^ (col & 7);
                bv[n2] = *(const bf16x8*)&U.g.Bs[col * 64 + pc * 8];
            }
            #pragma unroll
            for (int m2 = 0; m2 < 4; ++m2)
                #pragma unroll
                for (int n2 = 0; n2 < 4; ++n2)
                    acc[m2][n2] = mfma16(af[m2], bv[n2], acc[m2][n2]);
        }
        __syncthreads();
        #pragma unroll
        for (int m2 = 0; m2 < 4; ++m2)
            #pragma unroll
            for (int n2 = 0; n2 < 4; ++n2) {
                const int col = wc * 64 + n2 * 16 + lr;
                #pragma unroll
                for (int r = 0; r < 4; ++r) {
                    const int row = wr * 64 + m2 * 16 + lk * 4 + r;
                    U.Ct[row * 136 + col] = f2b(acc[m2][n2][r]);
                }
            }
        __syncthreads();
        #pragma unroll
        for (int q = 0; q < 8; ++q) {
            const int item = q * 256 + tid;
            const int dl = item & 127, kg = item >> 7;
            const int m = m0 + kg * 8;
            const int nn = m / 24, l0 = m % 24;
            const int kc = (h * 24 + l0) >> 3;
            const int ks = kc >> 2;
            const int dg = n0 + dl;
            const int kpos = (kc & 3) ^ ((dg >> 1) & 3);
            u32x4 uu;
            #pragma unroll
            for (int e = 0; e < 4; ++e)
                uu[e] = (unsigned int)U.Ct[(kg * 8 + 2 * e) * 136 + dl]
                      | ((unsigned int)U.Ct[(kg * 8 + 2 * e + 1) * 136 + dl] << 16);
            *(u32x4*)(Vout + (size_t)nn * 221184 + ks * 24576 + dg * 32 + kpos * 8) = uu;
        }
    } else {
        const int sub = bid >= 624;               // 0: S2e(+T), 1: S2n
        const int b = bid - (sub ? 624 : 432);
        const int n = b / NHEAD, h = b % NHEAD;
        const int qoff = sub ? 768 : 0, koff = sub ? 1536 : 0;
        float* Sout = sub ? S2n : S2e;
        for (int p = tid; p < 52 * 64; p += 256) {
            const int q = p >> 6, d = p & 63;
            U.s.sA[q][d] = b2f(QCb[(size_t)(n * 52 + q) * 1536 + qoff + h * 64 + d]);
        }
        for (int p = tid; p < 24 * 64; p += 256) {
            const int l = p >> 6, d = p & 63;
            U.s.sB[l][d] = b2f(LCb[(size_t)(n * 24 + l) * 3072 + koff + h * 64 + d]);
        }
        __syncthreads();
        for (int p = tid; p < 52 * 24; p += 256) {
            const int l = p / 52, q = p % 52;       // transposed: l slow, q fast
            float s = 0.f;
            #pragma unroll
            for (int d = 0; d < 64; ++d) s += U.s.sA[q][d] * U.s.sB[l][d];
            Sout[((size_t)(n * NHEAD + h) * 24 + l) * 52 + q] = s;
        }
        if (!sub && tid < 24) {
            float s = 0.f;
            #pragma unroll
            for (int d = 0; d < 64; ++d) s += e_bq[h * 64 + d] * U.s.sB[tid][d];
            Tb[((size_t)n * NHEAD + h) * 24 + tid] = s;
        }
    }
}

// ---------------------------------------------------------------------------
// attn_kernel v4b: full-width blocks (round-12) + true softmax/B-fetch overlap.
// Both B stages pre-issued; pre-softmax barrier is lgkmcnt-only (raw s_barrier)
// so the 96 KB of B loads stay in flight across the softmax VALU phase. The
// post-softmax __syncthreads (vmcnt0) finds them arrived. Loop issues ks+1
// only for ks>=1.
// [0,416): edge, block = (n, i-pair), 512 thr / 8 waves (2 i x 4 cg of 192).
// [416,432): node, block = (n).
// ---------------------------------------------------------------------------
__global__ __launch_bounds__(512)
void attn_kernel(const float* __restrict__ S2e, const float* __restrict__ Tb,
                 const float* __restrict__ S2n, const int* __restrict__ co_mask,
                 const unsigned short* __restrict__ VWe,
                 const unsigned short* __restrict__ VWn,
                 const float* __restrict__ ebo, const float* __restrict__ nbo,
                 unsigned short* __restrict__ EdgeBb,
                 unsigned short* __restrict__ NodePb)
{
    __shared__ __align__(16) char smem[161760];
    unsigned short* Pf = (unsigned short*)smem;              // [2][52*288] = 59904 B
    unsigned short* Bs = (unsigned short*)(smem + 59904);    // 2 x 24576 shorts = 98304 B
    float* SiT = (float*)(smem + 158208);                    // [2][288] = 2304 B
    unsigned char* cmb = (unsigned char*)(smem + 160512);    // 1248 B
    const int bid = blockIdx.x;
    const int tid = threadIdx.x;
    const int lane = tid & 63, w = tid >> 6;
    const int lr = lane & 15, lk = lane >> 4;

    if (bid < 416) {
        const int sw = (bid & 7) * 52 + (bid >> 3);          // XCD-contiguous n
        const int n = sw / 26;
        const int ip = sw % 26;
        const int i0 = ip * 2;
        const unsigned short* Bsrc = VWe + (size_t)n * 221184;
        const float* S2x = S2e + (size_t)n * NHEAD * 24 * 52;   // [h][l][j]

        // pre-issue B stages 0 AND 1 (stay in flight across softmax)
        #pragma unroll
        for (int s = 0; s < 2; ++s) {
            const unsigned short* src = Bsrc + (size_t)s * 24576;
            unsigned short* dstb = Bs + s * 24576;
            #pragma unroll
            for (int q = 0; q < 6; ++q) {
                const int c = q * 512 + tid;
                gl_lds16(src + c * 8, dstb + c * 8);
            }
        }
        for (int p = tid; p < 576; p += 512) {
            const int ii = p >= 288 ? 1 : 0;
            const int rl = p - ii * 288;                     // h*24 + l
            SiT[ii * 288 + rl] = S2x[(size_t)rl * 52 + i0 + ii]
                               + Tb[(size_t)n * 288 + rl];
        }
        for (int p = tid; p < 1248; p += 512)
            cmb[p] = (unsigned char)(co_mask[(size_t)n * 1248 + p] > 0);
        // lgkm-only barrier: orders SiT/cmb LDS writes, leaves B vmem in flight
        asm volatile("s_waitcnt lgkmcnt(0)" ::: "memory");
        __builtin_amdgcn_sched_barrier(0);
        __builtin_amdgcn_s_barrier();
        __builtin_amdgcn_sched_barrier(0);

        // softmax rows (ii,h,j) -> Pf[ii], swizzled chunk layout — ONCE
        for (int p = tid; p < 1248; p += 512) {
            const int ii = p >= 624 ? 1 : 0;
            const int rl = p - ii * 624;
            const int h = rl / 52, j = rl % 52;
            const float* Sc = S2x + (size_t)h * 1248 + j;    // stride 52 over l
            const float* st = SiT + ii * 288 + h * 24;
            float x[24]; float mx = -1e30f;
            #pragma unroll
            for (int l = 0; l < 24; ++l) {
                float v = (st[l] - Sc[l * 52]) * 0.125f;
                v = cmb[l * 52 + j] ? v : -1e9f;
                x[l] = v; mx = fmaxf(mx, v);
            }
            float sum = 0.f;
            #pragma unroll
            for (int l = 0; l < 24; ++l) { const float e = __expf(x[l] - mx); x[l] = e; sum += e; }
            const float inv = 1.f / sum;
            unsigned short* Prow = Pf + ii * 14976 + j * 288;
            const int swk = (j >> 1) & 3;
            #pragma unroll
            for (int c = 0; c < 3; ++c) {
                u32x4 u;
                #pragma unroll
                for (int m = 0; m < 4; ++m)
                    u[m] = pack2(x[c * 8 + 2 * m] * inv, x[c * 8 + 2 * m + 1] * inv);
                *(u32x4*)(Prow + (((3 * h + c) ^ swk) << 3)) = u;
            }
        }
        __syncthreads();                                     // drains vmcnt: stages 0,1 ready

        const int iw = w >> 2, cg = (w & 3) * 192;
        f32x4 acc[4][12] = {};
        for (int ks = 0; ks < 9; ++ks) {
            const int cur = ks & 1;
            if (ks >= 1 && ks < 8) {
                const unsigned short* src = Bsrc + (size_t)(ks + 1) * 24576;
                #pragma unroll
                for (int q = 0; q < 6; ++q) {
                    const int c = q * 512 + tid;
                    gl_lds16(src + c * 8, Bs + (cur ^ 1) * 24576 + c * 8);
                }
            }
            bf16x8 af[4];
            #pragma unroll
            for (int mt = 0; mt < 4; ++mt) {
                const int row = mt * 16 + lr;
                const int rowc = row < NOBJ ? row : 0;       // clamp pad rows
                af[mt] = *(const bf16x8*)(Pf + iw * 14976 + rowc * 288
                                          + (((ks * 4 + lk) ^ ((rowc >> 1) & 3)) << 3));
            }
            #pragma unroll
            for (int nt = 0; nt < 12; ++nt) {
                const int cl = cg + nt * 16 + lr;
                bf16x8 bv = *(const bf16x8*)(Bs + cur * 24576 + cl * 32
                                             + ((lk ^ ((cl >> 1) & 3)) << 3));
                #pragma unroll
                for (int mt = 0; mt < 4; ++mt)
                    acc[mt][nt] = mfma16(af[mt], bv, acc[mt][nt]);
            }
            __syncthreads();
        }

        #pragma unroll
        for (int nt = 0; nt < 12; ++nt) {
            float m = -1e30f;
            #pragma unroll
            for (int mt = 0; mt < 4; ++mt)
                #pragma unroll
                for (int r = 0; r < 4; ++r) {
                    const int row = mt * 16 + lk * 4 + r;
                    if (row < NOBJ) m = fmaxf(m, acc[mt][nt][r]);
                }
            m = fmaxf(m, __shfl_xor(m, 16));
            m = fmaxf(m, __shfl_xor(m, 32));
            if (lk == 0) {
                const int col = cg + nt * 16 + lr;
                EdgeBb[(size_t)(n * 52 + i0 + iw) * 768 + col] = f2b(m + ebo[col]);
            }
        }
    } else {
        const int n = bid - 416;
        const unsigned short* Bsrc = VWn + (size_t)n * 221184;
        const float* S2x = S2n + (size_t)n * NHEAD * 24 * 52;   // [h][l][j]

        #pragma unroll
        for (int s = 0; s < 2; ++s) {
            const unsigned short* src = Bsrc + (size_t)s * 24576;
            unsigned short* dstb = Bs + s * 24576;
            #pragma unroll
            for (int q = 0; q < 6; ++q) {
                const int c = q * 512 + tid;
                gl_lds16(src + c * 8, dstb + c * 8);
            }
        }
        for (int p = tid; p < 1248; p += 512)
            cmb[p] = (unsigned char)(co_mask[(size_t)n * 1248 + p] > 0);
        asm volatile("s_waitcnt lgkmcnt(0)" ::: "memory");
        __builtin_amdgcn_sched_barrier(0);
        __builtin_amdgcn_s_barrier();
        __builtin_amdgcn_sched_barrier(0);

        for (int p = tid; p < 624; p += 512) {
            const int h = p / 52, q = p % 52;
            const float* Sc = S2x + (size_t)h * 1248 + q;
            float x[24]; float mx = -1e30f;
            #pragma unroll
            for (int l = 0; l < 24; ++l) {
                float v = Sc[l * 52] * 0.125f;
                v = cmb[l * 52 + q] ? v : -1e9f;
                x[l] = v; mx = fmaxf(mx, v);
            }
            float sum = 0.f;
            #pragma unroll
            for (int l = 0; l < 24; ++l) { const float e = __expf(x[l] - mx); x[l] = e; sum += e; }
            const float inv = 1.f / sum;
            unsigned short* Prow = Pf + q * 288;
            const int swk = (q >> 1) & 3;
            #pragma unroll
            for (int c = 0; c < 3; ++c) {
                u32x4 u;
                #pragma unroll
                for (int m = 0; m < 4; ++m)
                    u[m] = pack2(x[c * 8 + 2 * m] * inv, x[c * 8 + 2 * m + 1] * inv);
                *(u32x4*)(Prow + (((3 * h + c) ^ swk) << 3)) = u;
            }
        }
        __syncthreads();

        const int cg = w * 96;
        f32x4 acc[4][6] = {};
        for (int ks = 0; ks < 9; ++ks) {
            const int cur = ks & 1;
            if (ks >= 1 && ks < 8) {
                const unsigned short* src = Bsrc + (size_t)(ks + 1) * 24576;
                #pragma unroll
                for (int q = 0; q < 6; ++q) {
                    const int c = q * 512 + tid;
                    gl_lds16(src + c * 8, Bs + (cur ^ 1) * 24576 + c * 8);
                }
            }
            bf16x8 af[4];
            #pragma unroll
            for (int mt = 0; mt < 4; ++mt) {
                const int row = mt * 16 + lr;
                const int rowc = row < NOBJ ? row : 0;
                af[mt] = *(const bf16x8*)(Pf + rowc * 288
                                          + (((ks * 4 + lk) ^ ((rowc >> 1) & 3)) << 3));
            }
            #pragma unroll
            for (int nt = 0; nt < 6; ++nt) {
                const int cl = cg + nt * 16 + lr;
                bf16x8 bv = *(const bf16x8*)(Bs + cur * 24576 + cl * 32
                                             + ((lk ^ ((cl >> 1) & 3)) << 3));
                #pragma unroll
                for (int mt = 0; mt < 4; ++mt)
                    acc[mt][nt] = mfma16(af[mt], bv, acc[mt][nt]);
            }
            __syncthreads();
        }

        #pragma unroll
        for (int nt = 0; nt < 6; ++nt) {
            const int col = cg + nt * 16 + lr;
            const float bv = nbo[col];
            #pragma unroll
            for (int mt = 0; mt < 4; ++mt)
                #pragma unroll
                for (int r = 0; r < 4; ++r) {
                    const int row = mt * 16 + lk * 4 + r;
                    if (row < NOBJ)
                        NodePb[(size_t)(n * 52 + row) * 768 + col] = f2b(acc[mt][nt][r] + bv);
                }
        }
    }
}

// ---------------------------------------------------------------------------
// ln_dual: rows 0..831 -> LN(obj+NodePb); rows 832..1663 -> LN(obj+EdgeBb)
// ---------------------------------------------------------------------------
__global__ __launch_bounds__(256)
void ln_dual_kernel(const float* __restrict__ obj,
                    const unsigned short* __restrict__ NodePb,
                    const unsigned short* __restrict__ EdgeBb,
                    const float* __restrict__ gq, const float* __restrict__ bq,
                    const float* __restrict__ ge, const float* __restrict__ be,
                    unsigned short* __restrict__ Fusedb)
{
    __shared__ float red[8];
    const int job = blockIdx.x >= 832;
    const int row = blockIdx.x - (job ? 832 : 0);
    const int tid = threadIdx.x;
    const unsigned short* x2 = (job ? EdgeBb : NodePb) + (size_t)row * 768;
    const float* x1 = obj + (size_t)row * 768;
    const float* g = job ? ge : gq;
    const float* bb = job ? be : bq;
    float v[3]; float s = 0.f;
    #pragma unroll
    for (int c = 0; c < 3; ++c) {
        const int col = tid + 256 * c;
        v[c] = x1[col] + b2f(x2[col]); s += v[c];
    }
    #pragma unroll
    for (int o = 32; o; o >>= 1) s += __shfl_xor(s, o);
    if ((tid & 63) == 0) red[tid >> 6] = s;
    __syncthreads();
    const float mean = (red[0] + red[1] + red[2] + red[3]) * (1.f / 768.f);
    float var = 0.f;
    #pragma unroll
    for (int c = 0; c < 3; ++c) { const float d = v[c] - mean; var += d * d; }
    #pragma unroll
    for (int o = 32; o; o >>= 1) var += __shfl_xor(var, o);
    __syncthreads();
    if ((tid & 63) == 0) red[4 + (tid >> 6)] = var;
    __syncthreads();
    const float vt = (red[4] + red[5] + red[6] + red[7]) * (1.f / 768.f);
    const float rs = rsqrtf(vt + 1e-5f);
    unsigned short* dst = Fusedb + (size_t)row * 1536 + (job ? 768 : 0);
    #pragma unroll
    for (int c = 0; c < 3; ++c) {
        const int col = tid + 256 * c;
        dst[col] = f2b((v[c] - mean) * rs * g[col] + bb[col]);
    }
}

// ---------------------------------------------------------------------------
// final LN: out = LN(Fusedb + sum of 4 ffn2 K-partials + ffn_b2)
// ---------------------------------------------------------------------------
__global__ __launch_bounds__(256)
void ln2_kernel(const unsigned short* __restrict__ x1b,
                const float* __restrict__ Hp, const float* __restrict__ b2,
                const float* __restrict__ g, const float* __restrict__ bb,
                float* __restrict__ dst)
{
    __shared__ float red[8];
    const int row = blockIdx.x, tid = threadIdx.x;
    float v[3]; float s = 0.f;
    #pragma unroll
    for (int c = 0; c < 3; ++c) {
        const int col = tid + 256 * c;
        const size_t o = (size_t)row * 768 + col;
        float h = Hp[o] + Hp[638976 + o] + Hp[2 * 638976 + o] + Hp[3 * 638976 + o];
        v[c] = b2f(x1b[(size_t)row * 1536 + col]) + h + b2[col];
        s += v[c];
    }
    #pragma unroll
    for (int o = 32; o; o >>= 1) s += __shfl_xor(s, o);
    if ((tid & 63) == 0) red[tid >> 6] = s;
    __syncthreads();
    const float mean = (red[0] + red[1] + red[2] + red[3]) * (1.f / 768.f);
    float var = 0.f;
    #pragma unroll
    for (int c = 0; c < 3; ++c) { const float d = v[c] - mean; var += d * d; }
    #pragma unroll
    for (int o = 32; o; o >>= 1) var += __shfl_xor(var, o);
    __syncthreads();
    if ((tid & 63) == 0) red[4 + (tid >> 6)] = var;
    __syncthreads();
    const float vt = (red[4] + red[5] + red[6] + red[7]) * (1.f / 768.f);
    const float rs = rsqrtf(vt + 1e-5f);
    #pragma unroll
    for (int c = 0; c < 3; ++c) {
        const int col = tid + 256 * c;
        dst[(size_t)row * 768 + col] = (v[c] - mean) * rs * g[col] + bb[col];
    }
}

// ---------------------------------------------------------------------------
extern "C" void kernel_launch(void* const* d_in, const int* in_sizes, int n_in,
                              void* d_out, int out_size, void* d_ws, size_t ws_size,
                              hipStream_t stream)
{
    (void)in_sizes; (void)n_in; (void)out_size; (void)ws_size;
    const float* lang  = (const float*)d_in[0];
    const float* obj   = (const float*)d_in[1];
    const int* co_mask = (const int*)d_in[4];
    const float* e_wq = (const float*)d_in[5];
    const float* e_bq = (const float*)d_in[6];
    const float* e_wk = (const float*)d_in[7];
    const float* e_bk = (const float*)d_in[8];
    const float* e_wv = (const float*)d_in[9];
    const float* e_bv = (const float*)d_in[10];
    const float* e_wo = (const float*)d_in[11];
    const float* e_bo = (const float*)d_in[12];
    const float* n_wq = (const float*)d_in[13];
    const float* n_bq = (const float*)d_in[14];
    const float* n_wk = (const float*)d_in[15];
    const float* n_bk = (const float*)d_in[16];
    const float* n_wv = (const float*)d_in[17];
    const float* n_bv = (const float*)d_in[18];
    const float* n_wo = (const float*)d_in[19];
    const float* n_bo = (const float*)d_in[20];
    const float* ffn_w1 = (const float*)d_in[21];
    const float* ffn_b1 = (const float*)d_in[22];
    const float* ffn_w2 = (const float*)d_in[23];
    const float* ffn_b2 = (const float*)d_in[24];
    const float* ln_e_g = (const float*)d_in[25];
    const float* ln_e_b = (const float*)d_in[26];
    const float* ln_q_g = (const float*)d_in[27];
    const float* ln_q_b = (const float*)d_in[28];
    const float* ln2_g = (const float*)d_in[29];
    const float* ln2_b = (const float*)d_in[30];
    float* out = (float*)d_out;

    // ---- workspace layout (flat, ~60 MB of ~256 MB) ----
    char* wsb = (char*)d_ws;
    unsigned short* Wqt   = (unsigned short*)(wsb + 0);          // [1536][768]
    unsigned short* Wlt   = (unsigned short*)(wsb + 2359296);    // [3072][768]
    unsigned short* Wet   = (unsigned short*)(wsb + 7077888);    // [768][768]
    unsigned short* Wot   = (unsigned short*)(wsb + 8257536);    // [768][768]
    unsigned short* W1t   = (unsigned short*)(wsb + 9437184);    // [2048][1536]
    unsigned short* W2t   = (unsigned short*)(wsb + 15728640);   // [768][2048]
    unsigned short* objb  = (unsigned short*)(wsb + 18874368);   // [832][768]
    unsigned short* langb = (unsigned short*)(wsb + 20152320);   // [384][768]
    float*          bqc   = (float*)(wsb + 20742144);            // [1536]
    float*          blc   = (float*)(wsb + 20748288);            // [3072]
    unsigned short* QCb   = (unsigned short*)(wsb + 20760576);   // [832][1536]
    unsigned short* LCb   = (unsigned short*)(wsb + 23316480);   // [384][3072]
    float*          S2e   = (float*)(wsb + 25675776);            // [16][12][24][52]
    float*          Tb    = (float*)(wsb + 26634240);            // [16][12][24]
    float*          S2n   = (float*)(wsb + 26652672);            // [16][12][24][52]
    unsigned short* VWe   = (unsigned short*)(wsb + 27611136);   // 16*221184
    unsigned short* VWn   = (unsigned short*)(wsb + 34689024);   // 16*221184
    unsigned short* NodePb= (unsigned short*)(wsb + 41766912);   // [832][768]
    unsigned short* EdgeBb= (unsigned short*)(wsb + 43044864);   // [832][768]
    unsigned short* Fusedb= (unsigned short*)(wsb + 44322816);   // [832][1536]
    unsigned short* H1b   = (unsigned short*)(wsb + 46878720);   // [832][2048]
    float*          Hp    = (float*)(wsb + 50286592);            // 4x[832][768] f32

    dim3 blk(256);
    // L1: pack square weights + activations + fused biases
    pack1_kernel<<<2069, blk, 0, stream>>>(
        e_wq, n_wq, e_wk, e_wv, n_wk, n_wv, n_wo, e_wo,
        Wqt, Wqt + 589824, Wlt, Wlt + 589824, Wlt + 2 * 589824, Wlt + 3 * 589824,
        Wot, Wet,
        obj, lang, n_bq, e_bk, e_bv, n_bk, n_bv, objb, langb, bqc, blc);
    // L2: both input projections + FFN weight transposes (independent filler)
    {
        GemmJob p0 = {objb, Wqt, bqc, nullptr, QCb, 768, 768, 1536, 768, 12, 156, 0, 0};
        GemmJob p1 = {langb, Wlt, blc, nullptr, LCb, 768, 768, 3072, 768, 24, 144, 0, 0};
        proj_pack_kernel<<<1452, blk, 0, stream>>>(p0, p1, ffn_w1, ffn_w2, W1t, W2t);
    }
    // L3: VWe + VWn (MFMA) + S2e/T + S2n (transposed S2 layout)
    mid3_kernel<<<816, blk, 0, stream>>>(QCb, LCb, Wet, Wot, e_bq,
                                         VWe, VWn, S2e, Tb, S2n);
    // L4: fused softmax + A@VW (edge 416 full-width + node 16)
    attn_kernel<<<432, dim3(512), 0, stream>>>(S2e, Tb, S2n, co_mask, VWe, VWn,
                                               e_bo, n_bo, EdgeBb, NodePb);
    // L5: both fuse layernorms
    ln_dual_kernel<<<1664, blk, 0, stream>>>(obj, NodePb, EdgeBb, ln_q_g, ln_q_b,
                                             ln_e_g, ln_e_b, Fusedb);
    // L6: FFN1
    {
        GemmJob p0 = {Fusedb, W1t, ffn_b1, nullptr, H1b, 1536, 1536, 2048, 1536, 16, 208, 1, 1};
        gemm_tn4<<<208, blk, 0, stream>>>(p0, p0, p0, p0);
    }
    // L7: FFN2 K-split x4 -> f32 partials
    {
        GemmJob q0 = {H1b,        W2t,        nullptr, Hp,               nullptr, 2048, 2048, 768, 512, 6, 78, 0, 0};
        GemmJob q1 = {H1b + 512,  W2t + 512,  nullptr, Hp + 638976,      nullptr, 2048, 2048, 768, 512, 6, 78, 0, 0};
        GemmJob q2 = {H1b + 1024, W2t + 1024, nullptr, Hp + 2 * 638976,  nullptr, 2048, 2048, 768, 512, 6, 78, 0, 0};
        GemmJob q3 = {H1b + 1536, W2t + 1536, nullptr, Hp + 3 * 638976,  nullptr, 2048, 2048, 768, 512, 6, 78, 0, 0};
        gemm_tn4<<<312, blk, 0, stream>>>(q0, q1, q2, q3);
    }
    // L8: final LN (sums partials + bias)
    ln2_kernel<<<832, blk, 0, stream>>>(Fusedb, Hp, ffn_b2, ln2_g, ln2_b, out);
}